// Round 1
// baseline (1354.362 us; speedup 1.0000x reference)
//
#include <hip/hip_runtime.h>
#include <math.h>

#define CH 64   // channels (C_IN == C_OUT == 64)

// ---------------- Laplacian weights ----------------

__global__ __launch_bounds__(256) void k_deg(const int* __restrict__ src,
                                             const float* __restrict__ w,
                                             float* __restrict__ deg, int E) {
    int i = blockIdx.x * 256 + threadIdx.x;
    if (i < E) atomicAdd(&deg[src[i]], w[i]);
}

__global__ __launch_bounds__(256) void k_dis(float* __restrict__ deg, int N) {
    int i = blockIdx.x * 256 + threadIdx.x;
    if (i < N) {
        float d = deg[i];
        deg[i] = (d > 0.f) ? rsqrtf(fmaxf(d, 1e-12f)) : 0.f;
    }
}

__global__ __launch_bounds__(256) void k_lw(const int* __restrict__ src,
                                            const int* __restrict__ dst,
                                            const float* __restrict__ w,
                                            const float* __restrict__ dis,
                                            float* __restrict__ lw, int E) {
    int i = blockIdx.x * 256 + threadIdx.x;
    if (i < E) lw[i] = -dis[src[i]] * w[i] * dis[dst[i]];
}

// ---------------- Sparse propagation: out[dst] += lw[e] * t[src] ----------------
// one wave (64 lanes) per edge, lane = channel -> coalesced 256B gather + scatter

__global__ __launch_bounds__(256) void k_prop(const int* __restrict__ src,
                                              const int* __restrict__ dst,
                                              const float* __restrict__ lw,
                                              const float* __restrict__ t,
                                              float* __restrict__ out, int E) {
    int i = blockIdx.x * 256 + threadIdx.x;
    int e = i >> 6;
    int c = i & 63;
    if (e < E) {
        float v = lw[e] * t[(long long)src[e] * CH + c];
        atomicAdd(&out[(long long)dst[e] * CH + c], v);
    }
}

// T2 = 2*P - T0 (in place on P)
__global__ __launch_bounds__(256) void k_combine(float* __restrict__ t2,
                                                 const float* __restrict__ t0,
                                                 int total4) {
    int i = blockIdx.x * 256 + threadIdx.x;
    if (i < total4) {
        float4 a = ((float4*)t2)[i];
        float4 b = ((const float4*)t0)[i];
        a.x = 2.f * a.x - b.x;
        a.y = 2.f * a.y - b.y;
        a.z = 2.f * a.z - b.z;
        a.w = 2.f * a.w - b.w;
        ((float4*)t2)[i] = a;
    }
}

// ---------------- GEMM helpers ----------------
// block = 256 threads; tile = 64 rows x 64 cols.
// thread: c = tid&63 (output col), rg = tid>>6 -> owns rows rg*16 .. rg*16+15.

__device__ __forceinline__ void load_tile(const float* __restrict__ src,
                                          float (*dst_s)[CH],
                                          int base, int N, int tid) {
    #pragma unroll
    for (int l = 0; l < 4; ++l) {
        int idx = tid + l * 256;        // float4 index within 64x64 tile
        int row = idx >> 4;
        int c4  = idx & 15;
        int grow = base + row;
        float4 v = make_float4(0.f, 0.f, 0.f, 0.f);
        if (grow < N) v = ((const float4*)src)[(long long)grow * 16 + c4];
        ((float4*)&dst_s[row][0])[c4] = v;
    }
}

__device__ __forceinline__ void load_w(const float* __restrict__ wp,
                                       float (*w_s)[CH], int tid) {
    #pragma unroll
    for (int l = 0; l < 4; ++l) {
        int idx = tid + l * 256;
        ((float4*)&w_s[0][0])[idx] = ((const float4*)wp)[idx];
    }
}

__device__ __forceinline__ void mm_apply(const float (*in_s)[CH],
                                         const float (*w_s)[CH],
                                         int c, int rbase, float* acc) {
    for (int k0 = 0; k0 < 64; k0 += 4) {
        float w0 = w_s[k0 + 0][c];
        float w1 = w_s[k0 + 1][c];
        float w2 = w_s[k0 + 2][c];
        float w3 = w_s[k0 + 3][c];
        #pragma unroll
        for (int i = 0; i < 16; ++i) {
            const float4 xv = *(const float4*)&in_s[rbase + i][k0];
            acc[i] = fmaf(xv.x, w0, fmaf(xv.y, w1, fmaf(xv.z, w2, fmaf(xv.w, w3, acc[i]))));
        }
    }
}

// ---------------- Pass A: Z, H*R, preH(x-part of H~) ----------------

__global__ __launch_bounds__(256) void k_gemmA(
    const float* __restrict__ X,  const float* __restrict__ TX1, const float* __restrict__ TX2,
    const float* __restrict__ H,  const float* __restrict__ TH1, const float* __restrict__ TH2,
    const float* __restrict__ Wxz, const float* __restrict__ Wxr, const float* __restrict__ Wxh,
    const float* __restrict__ Whz, const float* __restrict__ Whr,
    const float* __restrict__ bxz, const float* __restrict__ bxr, const float* __restrict__ bxh,
    const float* __restrict__ bhz, const float* __restrict__ bhr,
    float* __restrict__ Z, float* __restrict__ HR, float* __restrict__ preH, int N)
{
    __shared__ float in_s[64][CH];
    __shared__ float w_s[64][CH];
    const int tid = threadIdx.x;
    const int c  = tid & 63;
    const int rg = tid >> 6;
    const int rbase = rg * 16;
    const int base = blockIdx.x * 64;

    float accZ[16], accR[16], accH[16];
    const float bz = bxz[c] + bhz[c];
    const float br = bxr[c] + bhr[c];
    const float bh = bxh[c];
    #pragma unroll
    for (int i = 0; i < 16; ++i) { accZ[i] = bz; accR[i] = br; accH[i] = bh; }

    const float* ins[6] = { X, TX1, TX2, H, TH1, TH2 };

    for (int m = 0; m < 6; ++m) {
        __syncthreads();                 // previous iteration done with in_s/w_s
        load_tile(ins[m], in_s, base, N, tid);

        const float* wz = (m < 3) ? (Wxz + m * 4096) : (Whz + (m - 3) * 4096);
        const float* wr = (m < 3) ? (Wxr + m * 4096) : (Whr + (m - 3) * 4096);

        __syncthreads();
        load_w(wz, w_s, tid);
        __syncthreads();
        mm_apply(in_s, w_s, c, rbase, accZ);

        __syncthreads();
        load_w(wr, w_s, tid);
        __syncthreads();
        mm_apply(in_s, w_s, c, rbase, accR);

        if (m < 3) {
            __syncthreads();
            load_w(Wxh + m * 4096, w_s, tid);
            __syncthreads();
            mm_apply(in_s, w_s, c, rbase, accH);
        }
    }

    #pragma unroll
    for (int i = 0; i < 16; ++i) {
        int grow = base + rbase + i;
        if (grow < N) {
            long long o = (long long)grow * CH + c;
            float z = 1.f / (1.f + expf(-accZ[i]));
            float r = 1.f / (1.f + expf(-accR[i]));
            float h = H[o];
            Z[o]    = z;
            HR[o]   = h * r;
            preH[o] = accH[i];
        }
    }
}

// ---------------- Pass B: H_new = Z*H + (1-Z)*tanh(preH + hh-conv(H*R)) ----------------

__global__ __launch_bounds__(256) void k_gemmB(
    const float* __restrict__ HRin, const float* __restrict__ T1, const float* __restrict__ T2,
    const float* __restrict__ Whh, const float* __restrict__ bhh,
    const float* __restrict__ Z, const float* __restrict__ H,
    const float* __restrict__ preH, float* __restrict__ out, int N)
{
    __shared__ float in_s[64][CH];
    __shared__ float w_s[64][CH];
    const int tid = threadIdx.x;
    const int c  = tid & 63;
    const int rg = tid >> 6;
    const int rbase = rg * 16;
    const int base = blockIdx.x * 64;

    float acc[16];
    const float bh = bhh[c];
    #pragma unroll
    for (int i = 0; i < 16; ++i) {
        int grow = base + rbase + i;
        float p = (grow < N) ? preH[(long long)grow * CH + c] : 0.f;
        acc[i] = p + bh;
    }

    const float* ins[3] = { HRin, T1, T2 };
    for (int m = 0; m < 3; ++m) {
        __syncthreads();
        load_tile(ins[m], in_s, base, N, tid);
        __syncthreads();
        load_w(Whh + m * 4096, w_s, tid);
        __syncthreads();
        mm_apply(in_s, w_s, c, rbase, acc);
    }

    #pragma unroll
    for (int i = 0; i < 16; ++i) {
        int grow = base + rbase + i;
        if (grow < N) {
            long long o = (long long)grow * CH + c;
            float z = Z[o];
            float h = H[o];
            out[o] = z * h + (1.f - z) * tanhf(acc[i]);
        }
    }
}

// ---------------- launch ----------------

extern "C" void kernel_launch(void* const* d_in, const int* in_sizes, int n_in,
                              void* d_out, int out_size, void* d_ws, size_t ws_size,
                              hipStream_t stream) {
    const float* X   = (const float*)d_in[0];
    const int*   ei  = (const int*)d_in[1];
    const float* ew  = (const float*)d_in[2];
    const float* H   = (const float*)d_in[3];
    const float* Wxz = (const float*)d_in[4];
    const float* bxz = (const float*)d_in[5];
    const float* Whz = (const float*)d_in[6];
    const float* bhz = (const float*)d_in[7];
    const float* Wxr = (const float*)d_in[8];
    const float* bxr = (const float*)d_in[9];
    const float* Whr = (const float*)d_in[10];
    const float* bhr = (const float*)d_in[11];
    const float* Wxh = (const float*)d_in[12];
    const float* bxh = (const float*)d_in[13];
    const float* Whh = (const float*)d_in[14];
    const float* bhh = (const float*)d_in[15];

    const int N = in_sizes[0] / CH;
    const int E = in_sizes[2];
    const int NC = N * CH;

    const int* srcI = ei;
    const int* dstI = ei + E;

    float* ws = (float*)d_ws;
    float* lw   = ws;                       // E
    float* deg  = ws + E;                   // N
    size_t nb = ((size_t)(E + N) + 15) & ~(size_t)15;
    float* TX1  = ws + nb + 0ll * NC;
    float* TX2  = ws + nb + 1ll * NC;
    float* TH1  = ws + nb + 2ll * NC;      // reused as THR1
    float* TH2  = ws + nb + 3ll * NC;      // reused as THR2
    float* Zb   = ws + nb + 4ll * NC;
    float* HRb  = ws + nb + 5ll * NC;
    float* preH = ws + nb + 6ll * NC;

    const int bE  = (E + 255) / 256;
    const int bN  = (N + 255) / 256;
    const int bP  = (E * 64 + 255) / 256;
    const int b4  = (NC / 4 + 255) / 256;
    const int bG  = (N + 63) / 64;

    // Laplacian weights
    hipMemsetAsync(deg, 0, (size_t)N * sizeof(float), stream);
    k_deg<<<bE, 256, 0, stream>>>(srcI, ew, deg, E);
    k_dis<<<bN, 256, 0, stream>>>(deg, N);
    k_lw<<<bE, 256, 0, stream>>>(srcI, dstI, ew, deg, lw, E);

    // Chebyshev bases for X
    hipMemsetAsync(TX1, 0, (size_t)NC * sizeof(float), stream);
    k_prop<<<bP, 256, 0, stream>>>(srcI, dstI, lw, X, TX1, E);
    hipMemsetAsync(TX2, 0, (size_t)NC * sizeof(float), stream);
    k_prop<<<bP, 256, 0, stream>>>(srcI, dstI, lw, TX1, TX2, E);
    k_combine<<<b4, 256, 0, stream>>>(TX2, X, NC / 4);

    // Chebyshev bases for H
    hipMemsetAsync(TH1, 0, (size_t)NC * sizeof(float), stream);
    k_prop<<<bP, 256, 0, stream>>>(srcI, dstI, lw, H, TH1, E);
    hipMemsetAsync(TH2, 0, (size_t)NC * sizeof(float), stream);
    k_prop<<<bP, 256, 0, stream>>>(srcI, dstI, lw, TH1, TH2, E);
    k_combine<<<b4, 256, 0, stream>>>(TH2, H, NC / 4);

    // Pass A: Z, H*R, preH
    k_gemmA<<<bG, 256, 0, stream>>>(X, TX1, TX2, H, TH1, TH2,
                                    Wxz, Wxr, Wxh, Whz, Whr,
                                    bxz, bxr, bxh, bhz, bhr,
                                    Zb, HRb, preH, N);

    // Chebyshev bases for H*R (reuse TH1/TH2)
    hipMemsetAsync(TH1, 0, (size_t)NC * sizeof(float), stream);
    k_prop<<<bP, 256, 0, stream>>>(srcI, dstI, lw, HRb, TH1, E);
    hipMemsetAsync(TH2, 0, (size_t)NC * sizeof(float), stream);
    k_prop<<<bP, 256, 0, stream>>>(srcI, dstI, lw, TH1, TH2, E);
    k_combine<<<b4, 256, 0, stream>>>(TH2, HRb, NC / 4);

    // Pass B: H_new
    k_gemmB<<<bG, 256, 0, stream>>>(HRb, TH1, TH2, Whh, bhh,
                                    Zb, H, preH, (float*)d_out, N);
}

// Round 2
// 725.842 us; speedup vs baseline: 1.8659x; 1.8659x over previous
//
#include <hip/hip_runtime.h>
#include <math.h>

#define CH 64   // channels (C_IN == C_OUT == 64)

// ---------------- degree / normalization ----------------

__global__ __launch_bounds__(256) void k_deg(const int* __restrict__ src,
                                             const float* __restrict__ w,
                                             float* __restrict__ deg, int E) {
    int i = blockIdx.x * 256 + threadIdx.x;
    if (i < E) atomicAdd(&deg[src[i]], w[i]);
}

__global__ __launch_bounds__(256) void k_dis(float* __restrict__ deg, int N) {
    int i = blockIdx.x * 256 + threadIdx.x;
    if (i < N) {
        float d = deg[i];
        deg[i] = (d > 0.f) ? rsqrtf(fmaxf(d, 1e-12f)) : 0.f;
    }
}

// ---------------- CSR build (group edges by dst) ----------------

__global__ __launch_bounds__(256) void k_hist(const int* __restrict__ dst,
                                              int* __restrict__ cnt, int E) {
    int i = blockIdx.x * 256 + threadIdx.x;
    if (i < E) atomicAdd(&cnt[dst[i]], 1);
}

// single-block scan over N counts -> rowptr (exclusive), cnt becomes fill cursor
__global__ __launch_bounds__(1024) void k_scan(int* __restrict__ cnt,
                                               int* __restrict__ rowptr, int N) {
    __shared__ int smem[1024];
    __shared__ int carry_s;
    if (threadIdx.x == 0) carry_s = 0;
    __syncthreads();
    for (int base = 0; base < N; base += 1024) {
        int i = base + threadIdx.x;
        int v = (i < N) ? cnt[i] : 0;
        smem[threadIdx.x] = v;
        __syncthreads();
        for (int off = 1; off < 1024; off <<= 1) {
            int t = (threadIdx.x >= off) ? smem[threadIdx.x - off] : 0;
            __syncthreads();
            smem[threadIdx.x] += t;
            __syncthreads();
        }
        int carry = carry_s;
        int excl = carry + smem[threadIdx.x] - v;
        if (i < N) { rowptr[i] = excl; cnt[i] = excl; }
        __syncthreads();
        if (threadIdx.x == 0) carry_s = carry + smem[1023];
        __syncthreads();
    }
    if (threadIdx.x == 0) rowptr[N] = carry_s;
}

// scatter edges into CSR order; fold the Laplacian weight in here
__global__ __launch_bounds__(256) void k_scatter(const int* __restrict__ src,
                                                 const int* __restrict__ dst,
                                                 const float* __restrict__ w,
                                                 const float* __restrict__ dis,
                                                 int* __restrict__ fill,
                                                 int* __restrict__ esrc,
                                                 float* __restrict__ elw, int E) {
    int e = blockIdx.x * 256 + threadIdx.x;
    if (e < E) {
        int d = dst[e], s = src[e];
        int pos = atomicAdd(&fill[d], 1);
        esrc[pos] = s;
        elw[pos] = -dis[s] * w[e] * dis[d];
    }
}

// ---------------- CSR propagation: out[n] = sum_{e: dst=n} lw[e] * t[src[e]] ----
// one wave per node, lane = channel; register accumulation, single coalesced write

__global__ __launch_bounds__(256) void k_propcsr(const int* __restrict__ rowptr,
                                                 const int* __restrict__ esrc,
                                                 const float* __restrict__ elw,
                                                 const float* __restrict__ t,
                                                 float* __restrict__ out, int N) {
    int wid = (blockIdx.x * 256 + threadIdx.x) >> 6;
    int lane = threadIdx.x & 63;
    if (wid >= N) return;
    int beg = rowptr[wid], end = rowptr[wid + 1];
    float acc = 0.f;
    int j = beg;
    for (; j + 1 < end; j += 2) {
        int s0 = esrc[j], s1 = esrc[j + 1];
        float l0 = elw[j], l1 = elw[j + 1];
        float v0 = t[s0 * CH + lane];
        float v1 = t[s1 * CH + lane];
        acc = fmaf(l0, v0, acc);
        acc = fmaf(l1, v1, acc);
    }
    if (j < end) acc = fmaf(elw[j], t[esrc[j] * CH + lane], acc);
    out[wid * CH + lane] = acc;
}

// same, fused Chebyshev combine: out = 2*prop(t) - t0
__global__ __launch_bounds__(256) void k_propcsr2(const int* __restrict__ rowptr,
                                                  const int* __restrict__ esrc,
                                                  const float* __restrict__ elw,
                                                  const float* __restrict__ t,
                                                  const float* __restrict__ t0,
                                                  float* __restrict__ out, int N) {
    int wid = (blockIdx.x * 256 + threadIdx.x) >> 6;
    int lane = threadIdx.x & 63;
    if (wid >= N) return;
    int beg = rowptr[wid], end = rowptr[wid + 1];
    float acc = 0.f;
    int j = beg;
    for (; j + 1 < end; j += 2) {
        int s0 = esrc[j], s1 = esrc[j + 1];
        float l0 = elw[j], l1 = elw[j + 1];
        float v0 = t[s0 * CH + lane];
        float v1 = t[s1 * CH + lane];
        acc = fmaf(l0, v0, acc);
        acc = fmaf(l1, v1, acc);
    }
    if (j < end) acc = fmaf(elw[j], t[esrc[j] * CH + lane], acc);
    out[wid * CH + lane] = 2.f * acc - t0[wid * CH + lane];
}

// ---------------- GEMM helpers ----------------
// block = 256 threads; tile = 64 rows x 64 cols.
// thread: c = tid&63 (output col), rg = tid>>6 -> owns rows rg*16 .. rg*16+15.

__device__ __forceinline__ void load_tile(const float* __restrict__ src,
                                          float (*dst_s)[CH],
                                          int base, int N, int tid) {
    #pragma unroll
    for (int l = 0; l < 4; ++l) {
        int idx = tid + l * 256;        // float4 index within 64x64 tile
        int row = idx >> 4;
        int c4  = idx & 15;
        int grow = base + row;
        float4 v = make_float4(0.f, 0.f, 0.f, 0.f);
        if (grow < N) v = ((const float4*)src)[(long long)grow * 16 + c4];
        ((float4*)&dst_s[row][0])[c4] = v;
    }
}

__device__ __forceinline__ void load_w(const float* __restrict__ wp,
                                       float (*w_s)[CH], int tid) {
    #pragma unroll
    for (int l = 0; l < 4; ++l) {
        int idx = tid + l * 256;
        ((float4*)&w_s[0][0])[idx] = ((const float4*)wp)[idx];
    }
}

// fused: 3 weight matrices against one input tile (in_s read once)
__device__ __forceinline__ void mm3(const float (*in_s)[CH],
                                    const float (*w0)[CH], const float (*w1)[CH],
                                    const float (*w2)[CH],
                                    int c, int rbase,
                                    float* a0, float* a1, float* a2) {
    for (int k0 = 0; k0 < 64; k0 += 4) {
        float z0 = w0[k0+0][c], z1 = w0[k0+1][c], z2 = w0[k0+2][c], z3 = w0[k0+3][c];
        float r0 = w1[k0+0][c], r1 = w1[k0+1][c], r2 = w1[k0+2][c], r3 = w1[k0+3][c];
        float h0 = w2[k0+0][c], h1 = w2[k0+1][c], h2 = w2[k0+2][c], h3 = w2[k0+3][c];
        #pragma unroll
        for (int i = 0; i < 16; ++i) {
            const float4 xv = *(const float4*)&in_s[rbase + i][k0];
            a0[i] = fmaf(xv.x, z0, fmaf(xv.y, z1, fmaf(xv.z, z2, fmaf(xv.w, z3, a0[i]))));
            a1[i] = fmaf(xv.x, r0, fmaf(xv.y, r1, fmaf(xv.z, r2, fmaf(xv.w, r3, a1[i]))));
            a2[i] = fmaf(xv.x, h0, fmaf(xv.y, h1, fmaf(xv.z, h2, fmaf(xv.w, h3, a2[i]))));
        }
    }
}

__device__ __forceinline__ void mm2(const float (*in_s)[CH],
                                    const float (*w0)[CH], const float (*w1)[CH],
                                    int c, int rbase, float* a0, float* a1) {
    for (int k0 = 0; k0 < 64; k0 += 4) {
        float z0 = w0[k0+0][c], z1 = w0[k0+1][c], z2 = w0[k0+2][c], z3 = w0[k0+3][c];
        float r0 = w1[k0+0][c], r1 = w1[k0+1][c], r2 = w1[k0+2][c], r3 = w1[k0+3][c];
        #pragma unroll
        for (int i = 0; i < 16; ++i) {
            const float4 xv = *(const float4*)&in_s[rbase + i][k0];
            a0[i] = fmaf(xv.x, z0, fmaf(xv.y, z1, fmaf(xv.z, z2, fmaf(xv.w, z3, a0[i]))));
            a1[i] = fmaf(xv.x, r0, fmaf(xv.y, r1, fmaf(xv.z, r2, fmaf(xv.w, r3, a1[i]))));
        }
    }
}

// ---------------- Pass A: Z, H*R, preH(x-part of H~) ----------------

__global__ __launch_bounds__(256) void k_gemmA(
    const float* __restrict__ X,  const float* __restrict__ TX1, const float* __restrict__ TX2,
    const float* __restrict__ H,  const float* __restrict__ TH1, const float* __restrict__ TH2,
    const float* __restrict__ Wxz, const float* __restrict__ Wxr, const float* __restrict__ Wxh,
    const float* __restrict__ Whz, const float* __restrict__ Whr,
    const float* __restrict__ bxz, const float* __restrict__ bxr, const float* __restrict__ bxh,
    const float* __restrict__ bhz, const float* __restrict__ bhr,
    float* __restrict__ Z, float* __restrict__ HR, float* __restrict__ preH, int N)
{
    __shared__ float in_s[64][CH];
    __shared__ float w_s0[64][CH];
    __shared__ float w_s1[64][CH];
    __shared__ float w_s2[64][CH];
    const int tid = threadIdx.x;
    const int c  = tid & 63;
    const int rg = tid >> 6;
    const int rbase = rg * 16;
    const int base = blockIdx.x * 64;

    float accZ[16], accR[16], accH[16];
    const float bz = bxz[c] + bhz[c];
    const float br = bxr[c] + bhr[c];
    const float bh = bxh[c];
    #pragma unroll
    for (int i = 0; i < 16; ++i) { accZ[i] = bz; accR[i] = br; accH[i] = bh; }

    const float* ins[6] = { X, TX1, TX2, H, TH1, TH2 };

    for (int m = 0; m < 6; ++m) {
        __syncthreads();                 // previous iteration done with tiles
        load_tile(ins[m], in_s, base, N, tid);
        if (m < 3) {
            load_w(Wxz + m * 4096, w_s0, tid);
            load_w(Wxr + m * 4096, w_s1, tid);
            load_w(Wxh + m * 4096, w_s2, tid);
        } else {
            load_w(Whz + (m - 3) * 4096, w_s0, tid);
            load_w(Whr + (m - 3) * 4096, w_s1, tid);
        }
        __syncthreads();
        if (m < 3) mm3(in_s, w_s0, w_s1, w_s2, c, rbase, accZ, accR, accH);
        else       mm2(in_s, w_s0, w_s1, c, rbase, accZ, accR);
    }

    #pragma unroll
    for (int i = 0; i < 16; ++i) {
        int grow = base + rbase + i;
        if (grow < N) {
            long long o = (long long)grow * CH + c;
            float z = 1.f / (1.f + expf(-accZ[i]));
            float r = 1.f / (1.f + expf(-accR[i]));
            float h = H[o];
            Z[o]    = z;
            HR[o]   = h * r;
            preH[o] = accH[i];
        }
    }
}

// ---------------- Pass B: H_new = Z*H + (1-Z)*tanh(preH + hh-conv(H*R)) ----------------
// preH lives in d_out; each thread reads its own preH[o] then overwrites with H_new.

__global__ __launch_bounds__(256) void k_gemmB(
    const float* __restrict__ HRin, const float* __restrict__ T1, const float* __restrict__ T2,
    const float* __restrict__ Whh, const float* __restrict__ bhh,
    const float* __restrict__ Z, const float* __restrict__ H,
    float* __restrict__ out /* holds preH on entry */, int N)
{
    __shared__ float in_s[64][CH];
    __shared__ float w_s[64][CH];
    const int tid = threadIdx.x;
    const int c  = tid & 63;
    const int rg = tid >> 6;
    const int rbase = rg * 16;
    const int base = blockIdx.x * 64;

    float acc[16];
    const float bh = bhh[c];
    #pragma unroll
    for (int i = 0; i < 16; ++i) {
        int grow = base + rbase + i;
        float p = (grow < N) ? out[(long long)grow * CH + c] : 0.f;
        acc[i] = p + bh;
    }

    const float* ins[3] = { HRin, T1, T2 };
    for (int m = 0; m < 3; ++m) {
        __syncthreads();
        load_tile(ins[m], in_s, base, N, tid);
        load_w(Whh + m * 4096, w_s, tid);
        __syncthreads();
        for (int k0 = 0; k0 < 64; k0 += 4) {
            float w0 = w_s[k0+0][c], w1 = w_s[k0+1][c], w2 = w_s[k0+2][c], w3 = w_s[k0+3][c];
            #pragma unroll
            for (int i = 0; i < 16; ++i) {
                const float4 xv = *(const float4*)&in_s[rbase + i][k0];
                acc[i] = fmaf(xv.x, w0, fmaf(xv.y, w1, fmaf(xv.z, w2, fmaf(xv.w, w3, acc[i]))));
            }
        }
    }

    #pragma unroll
    for (int i = 0; i < 16; ++i) {
        int grow = base + rbase + i;
        if (grow < N) {
            long long o = (long long)grow * CH + c;
            float z = Z[o];
            float h = H[o];
            out[o] = z * h + (1.f - z) * tanhf(acc[i]);
        }
    }
}

// ---------------- launch ----------------

extern "C" void kernel_launch(void* const* d_in, const int* in_sizes, int n_in,
                              void* d_out, int out_size, void* d_ws, size_t ws_size,
                              hipStream_t stream) {
    const float* X   = (const float*)d_in[0];
    const int*   ei  = (const int*)d_in[1];
    const float* ew  = (const float*)d_in[2];
    const float* H   = (const float*)d_in[3];
    const float* Wxz = (const float*)d_in[4];
    const float* bxz = (const float*)d_in[5];
    const float* Whz = (const float*)d_in[6];
    const float* bhz = (const float*)d_in[7];
    const float* Wxr = (const float*)d_in[8];
    const float* bxr = (const float*)d_in[9];
    const float* Whr = (const float*)d_in[10];
    const float* bhr = (const float*)d_in[11];
    const float* Wxh = (const float*)d_in[12];
    const float* bxh = (const float*)d_in[13];
    const float* Whh = (const float*)d_in[14];
    const float* bhh = (const float*)d_in[15];

    const int N = in_sizes[0] / CH;
    const int E = in_sizes[2];
    const long long NC = (long long)N * CH;

    const int* srcI = ei;
    const int* dstI = ei + E;

    // ---- workspace layout (float units) ----
    float* ws = (float*)d_ws;
    int*   rowptr = (int*)ws;                    // N+1
    int*   esrc   = (int*)(ws + (N + 1));        // E
    float* elw    = ws + (N + 1) + E;            // E
    float* deg    = ws + (N + 1) + 2 * (long long)E;       // N
    int*   cnt    = (int*)(deg + N);             // N (becomes fill cursor)
    long long nb = ((N + 1) + 2 * (long long)E + 2 * (long long)N + 15) & ~15ll;
    float* TX1  = ws + nb + 0 * NC;
    float* TX2  = ws + nb + 1 * NC;
    float* TH1  = ws + nb + 2 * NC;      // reused for H*R bases
    float* TH2  = ws + nb + 3 * NC;
    float* Zb   = ws + nb + 4 * NC;
    float* HRb  = ws + nb + 5 * NC;
    float* preH = (float*)d_out;         // scratch in d_out, overwritten by gemmB

    const int bE = (E + 255) / 256;
    const int bN = (N + 255) / 256;
    const int bW = ((N * 64) + 255) / 256;   // one wave per node
    const int bG = (N + 63) / 64;

    // degree + rsqrt
    hipMemsetAsync(deg, 0, (size_t)N * sizeof(float), stream);
    hipMemsetAsync(cnt, 0, (size_t)N * sizeof(int), stream);
    k_deg<<<bE, 256, 0, stream>>>(srcI, ew, deg, E);
    k_dis<<<bN, 256, 0, stream>>>(deg, N);

    // CSR build (by dst)
    k_hist<<<bE, 256, 0, stream>>>(dstI, cnt, E);
    k_scan<<<1, 1024, 0, stream>>>(cnt, rowptr, N);
    k_scatter<<<bE, 256, 0, stream>>>(srcI, dstI, ew, deg, cnt, esrc, elw, E);

    // Chebyshev bases for X
    k_propcsr <<<bW, 256, 0, stream>>>(rowptr, esrc, elw, X, TX1, N);
    k_propcsr2<<<bW, 256, 0, stream>>>(rowptr, esrc, elw, TX1, X, TX2, N);

    // Chebyshev bases for H
    k_propcsr <<<bW, 256, 0, stream>>>(rowptr, esrc, elw, H, TH1, N);
    k_propcsr2<<<bW, 256, 0, stream>>>(rowptr, esrc, elw, TH1, H, TH2, N);

    // Pass A: Z, H*R, preH
    k_gemmA<<<bG, 256, 0, stream>>>(X, TX1, TX2, H, TH1, TH2,
                                    Wxz, Wxr, Wxh, Whz, Whr,
                                    bxz, bxr, bxh, bhz, bhr,
                                    Zb, HRb, preH, N);

    // Chebyshev bases for H*R (reuse TH1/TH2)
    k_propcsr <<<bW, 256, 0, stream>>>(rowptr, esrc, elw, HRb, TH1, N);
    k_propcsr2<<<bW, 256, 0, stream>>>(rowptr, esrc, elw, TH1, HRb, TH2, N);

    // Pass B: H_new
    k_gemmB<<<bG, 256, 0, stream>>>(HRb, TH1, TH2, Whh, bhh,
                                    Zb, H, (float*)d_out, N);
}

// Round 3
// 499.057 us; speedup vs baseline: 2.7138x; 1.4544x over previous
//
#include <hip/hip_runtime.h>
#include <math.h>

#define CH 64   // channels (C_IN == C_OUT == 64)

typedef __attribute__((ext_vector_type(8))) short bf16x8;
typedef __attribute__((ext_vector_type(4))) float f32x4;

static __device__ __forceinline__ float bf2f(ushort u) {
    union { unsigned int i; float f; } v; v.i = ((unsigned int)u) << 16; return v.f;
}
static __device__ __forceinline__ ushort f2bf(float f) {
    union { float f; unsigned int i; } v; v.f = f;
    unsigned int lsb = (v.i >> 16) & 1;
    v.i += 0x7fffu + lsb;               // round-to-nearest-even
    return (ushort)(v.i >> 16);
}

// ---------------- degree / normalization ----------------

__global__ __launch_bounds__(256) void k_deg(const int* __restrict__ src,
                                             const float* __restrict__ w,
                                             float* __restrict__ deg, int E) {
    int i = blockIdx.x * 256 + threadIdx.x;
    if (i < E) atomicAdd(&deg[src[i]], w[i]);
}

__global__ __launch_bounds__(256) void k_dis(float* __restrict__ deg, int N) {
    int i = blockIdx.x * 256 + threadIdx.x;
    if (i < N) {
        float d = deg[i];
        deg[i] = (d > 0.f) ? rsqrtf(fmaxf(d, 1e-12f)) : 0.f;
    }
}

// ---------------- CSR build (group edges by dst) ----------------

__global__ __launch_bounds__(256) void k_hist(const int* __restrict__ dst,
                                              int* __restrict__ cnt, int E) {
    int i = blockIdx.x * 256 + threadIdx.x;
    if (i < E) atomicAdd(&cnt[dst[i]], 1);
}

__global__ __launch_bounds__(1024) void k_scan(int* __restrict__ cnt,
                                               int* __restrict__ rowptr, int N) {
    __shared__ int smem[1024];
    __shared__ int carry_s;
    if (threadIdx.x == 0) carry_s = 0;
    __syncthreads();
    for (int base = 0; base < N; base += 1024) {
        int i = base + threadIdx.x;
        int v = (i < N) ? cnt[i] : 0;
        smem[threadIdx.x] = v;
        __syncthreads();
        for (int off = 1; off < 1024; off <<= 1) {
            int t = (threadIdx.x >= off) ? smem[threadIdx.x - off] : 0;
            __syncthreads();
            smem[threadIdx.x] += t;
            __syncthreads();
        }
        int carry = carry_s;
        int excl = carry + smem[threadIdx.x] - v;
        if (i < N) { rowptr[i] = excl; cnt[i] = excl; }
        __syncthreads();
        if (threadIdx.x == 0) carry_s = carry + smem[1023];
        __syncthreads();
    }
    if (threadIdx.x == 0) rowptr[N] = carry_s;
}

__global__ __launch_bounds__(256) void k_scatter(const int* __restrict__ src,
                                                 const int* __restrict__ dst,
                                                 const float* __restrict__ w,
                                                 const float* __restrict__ dis,
                                                 int* __restrict__ fill,
                                                 int* __restrict__ esrc,
                                                 float* __restrict__ elw, int E) {
    int e = blockIdx.x * 256 + threadIdx.x;
    if (e < E) {
        int d = dst[e], s = src[e];
        int pos = atomicAdd(&fill[d], 1);
        esrc[pos] = s;
        elw[pos] = -dis[s] * w[e] * dis[d];
    }
}

// ---------------- cast X,H to bf16 ----------------

__global__ __launch_bounds__(256) void k_cast2(const float4* __restrict__ X,
                                               const float4* __restrict__ H,
                                               ushort* __restrict__ Xb,
                                               ushort* __restrict__ Hb, int total4) {
    int i = blockIdx.x * 256 + threadIdx.x;
    if (i < total4) {
        float4 x = X[i], h = H[i];
        ushort4 xb, hb;
        xb.x = f2bf(x.x); xb.y = f2bf(x.y); xb.z = f2bf(x.z); xb.w = f2bf(x.w);
        hb.x = f2bf(h.x); hb.y = f2bf(h.y); hb.z = f2bf(h.z); hb.w = f2bf(h.w);
        ((ushort4*)Xb)[i] = xb;
        ((ushort4*)Hb)[i] = hb;
    }
}

// ---------------- pack weights into frag-ready bf16 blobs ----------------
// Bp[mtg][ct][lane][e], mtg: z=0..11, r=12..23, h(x)=24..29, hh=30..35
// k-slot convention: k = kt*32 + (lane>>4)*8 + e  (consistent A/B -> correct)

__global__ __launch_bounds__(256) void k_pack(
    const float* __restrict__ Wxz, const float* __restrict__ Whz,
    const float* __restrict__ Wxr, const float* __restrict__ Whr,
    const float* __restrict__ Wxh, const float* __restrict__ Whh,
    ushort* __restrict__ Bp)
{
    int mtg = blockIdx.x;
    int ct = threadIdx.x >> 6;
    int lane = threadIdx.x & 63;
    const float* W; int m, kt;
    if (mtg < 12)      { int l = mtg;      m = l >> 1; kt = l & 1; W = (m < 3) ? Wxz + m * 4096 : Whz + (m - 3) * 4096; }
    else if (mtg < 24) { int l = mtg - 12; m = l >> 1; kt = l & 1; W = (m < 3) ? Wxr + m * 4096 : Whr + (m - 3) * 4096; }
    else if (mtg < 30) { int l = mtg - 24; m = l >> 1; kt = l & 1; W = Wxh + m * 4096; }
    else               { int l = mtg - 30; m = l >> 1; kt = l & 1; W = Whh + m * 4096; }
    int cout = ct * 16 + (lane & 15);
    ushort* dst = Bp + ((((mtg * 4) + ct) * 64 + lane) << 3);
    #pragma unroll
    for (int e = 0; e < 8; ++e) {
        int cin = kt * 32 + ((lane >> 4) << 3) + e;
        dst[e] = f2bf(W[cin * 64 + cout]);
    }
}

// ---------------- CSR propagation (bf16 features) ----------------
// one wave per node, lane = channel

__global__ __launch_bounds__(256) void k_prop_dual(const int* __restrict__ rowptr,
                                                   const int* __restrict__ esrc,
                                                   const float* __restrict__ elw,
                                                   const ushort* __restrict__ tA,
                                                   const ushort* __restrict__ tB,
                                                   ushort* __restrict__ oA,
                                                   ushort* __restrict__ oB, int N) {
    int wid = (blockIdx.x * 256 + threadIdx.x) >> 6;
    int lane = threadIdx.x & 63;
    if (wid >= N) return;
    int beg = rowptr[wid], end = rowptr[wid + 1];
    float aA = 0.f, aB = 0.f;
    int j = beg;
    for (; j + 1 < end; j += 2) {
        int s0 = esrc[j], s1 = esrc[j + 1];
        float l0 = elw[j], l1 = elw[j + 1];
        aA = fmaf(l0, bf2f(tA[s0 * CH + lane]), aA);
        aB = fmaf(l0, bf2f(tB[s0 * CH + lane]), aB);
        aA = fmaf(l1, bf2f(tA[s1 * CH + lane]), aA);
        aB = fmaf(l1, bf2f(tB[s1 * CH + lane]), aB);
    }
    if (j < end) {
        int s = esrc[j]; float l = elw[j];
        aA = fmaf(l, bf2f(tA[s * CH + lane]), aA);
        aB = fmaf(l, bf2f(tB[s * CH + lane]), aB);
    }
    oA[wid * CH + lane] = f2bf(aA);
    oB[wid * CH + lane] = f2bf(aB);
}

// dual with fused Chebyshev combine: o = 2*prop(t) - t0
__global__ __launch_bounds__(256) void k_prop_dual2(const int* __restrict__ rowptr,
                                                    const int* __restrict__ esrc,
                                                    const float* __restrict__ elw,
                                                    const ushort* __restrict__ tA,
                                                    const ushort* __restrict__ tB,
                                                    const ushort* __restrict__ t0A,
                                                    const ushort* __restrict__ t0B,
                                                    ushort* __restrict__ oA,
                                                    ushort* __restrict__ oB, int N) {
    int wid = (blockIdx.x * 256 + threadIdx.x) >> 6;
    int lane = threadIdx.x & 63;
    if (wid >= N) return;
    int beg = rowptr[wid], end = rowptr[wid + 1];
    float aA = 0.f, aB = 0.f;
    int j = beg;
    for (; j + 1 < end; j += 2) {
        int s0 = esrc[j], s1 = esrc[j + 1];
        float l0 = elw[j], l1 = elw[j + 1];
        aA = fmaf(l0, bf2f(tA[s0 * CH + lane]), aA);
        aB = fmaf(l0, bf2f(tB[s0 * CH + lane]), aB);
        aA = fmaf(l1, bf2f(tA[s1 * CH + lane]), aA);
        aB = fmaf(l1, bf2f(tB[s1 * CH + lane]), aB);
    }
    if (j < end) {
        int s = esrc[j]; float l = elw[j];
        aA = fmaf(l, bf2f(tA[s * CH + lane]), aA);
        aB = fmaf(l, bf2f(tB[s * CH + lane]), aB);
    }
    int o = wid * CH + lane;
    oA[o] = f2bf(2.f * aA - bf2f(t0A[o]));
    oB[o] = f2bf(2.f * aB - bf2f(t0B[o]));
}

__global__ __launch_bounds__(256) void k_prop1(const int* __restrict__ rowptr,
                                               const int* __restrict__ esrc,
                                               const float* __restrict__ elw,
                                               const ushort* __restrict__ t,
                                               ushort* __restrict__ out, int N) {
    int wid = (blockIdx.x * 256 + threadIdx.x) >> 6;
    int lane = threadIdx.x & 63;
    if (wid >= N) return;
    int beg = rowptr[wid], end = rowptr[wid + 1];
    float acc = 0.f;
    int j = beg;
    for (; j + 1 < end; j += 2) {
        int s0 = esrc[j], s1 = esrc[j + 1];
        float l0 = elw[j], l1 = elw[j + 1];
        acc = fmaf(l0, bf2f(t[s0 * CH + lane]), acc);
        acc = fmaf(l1, bf2f(t[s1 * CH + lane]), acc);
    }
    if (j < end) acc = fmaf(elw[j], bf2f(t[esrc[j] * CH + lane]), acc);
    out[wid * CH + lane] = f2bf(acc);
}

__global__ __launch_bounds__(256) void k_prop2(const int* __restrict__ rowptr,
                                               const int* __restrict__ esrc,
                                               const float* __restrict__ elw,
                                               const ushort* __restrict__ t,
                                               const ushort* __restrict__ t0,
                                               ushort* __restrict__ out, int N) {
    int wid = (blockIdx.x * 256 + threadIdx.x) >> 6;
    int lane = threadIdx.x & 63;
    if (wid >= N) return;
    int beg = rowptr[wid], end = rowptr[wid + 1];
    float acc = 0.f;
    int j = beg;
    for (; j + 1 < end; j += 2) {
        int s0 = esrc[j], s1 = esrc[j + 1];
        float l0 = elw[j], l1 = elw[j + 1];
        acc = fmaf(l0, bf2f(t[s0 * CH + lane]), acc);
        acc = fmaf(l1, bf2f(t[s1 * CH + lane]), acc);
    }
    if (j < end) acc = fmaf(elw[j], bf2f(t[esrc[j] * CH + lane]), acc);
    int o = wid * CH + lane;
    out[o] = f2bf(2.f * acc - bf2f(t0[o]));
}

// ---------------- MFMA GEMM helpers ----------------
// wave computes 32 rows x 64 cols; k-slot: k = kt*32 + (lane>>4)*8 + e

static __device__ __forceinline__ bf16x8 ldA(const ushort* __restrict__ t,
                                             int row0, int lane, int kt, int N) {
    int row = row0 + (lane & 15);
    bf16x8 v = {};
    if (row < N) v = *(const bf16x8*)(t + (size_t)row * CH + kt * 32 + ((lane >> 4) << 3));
    return v;
}
static __device__ __forceinline__ bf16x8 ldB(const ushort* __restrict__ bp,
                                             int mt, int ct, int lane) {
    return *(const bf16x8*)(bp + ((((mt * 4) + ct) * 64 + lane) << 3));
}

#define MFMA(a, b, c) __builtin_amdgcn_mfma_f32_16x16x32_bf16(a, b, c, 0, 0, 0)

// ---------------- Pass A: Z(f32), HR(bf16), preH(f32 in d_out) ----------------

__global__ __launch_bounds__(256) void k_gA(
    const ushort* __restrict__ Xb, const ushort* __restrict__ T1x, const ushort* __restrict__ T2x,
    const ushort* __restrict__ Hb, const ushort* __restrict__ T1h, const ushort* __restrict__ T2h,
    const ushort* __restrict__ Bp,
    const float* __restrict__ bxz, const float* __restrict__ bhz,
    const float* __restrict__ bxr, const float* __restrict__ bhr,
    const float* __restrict__ bxh,
    const float* __restrict__ H,
    float* __restrict__ Zb, ushort* __restrict__ HRb, float* __restrict__ preH, int N)
{
    int wid = blockIdx.x * 4 + (threadIdx.x >> 6);
    int lane = threadIdx.x & 63;
    int row0 = wid * 32;
    if (row0 >= N) return;

    f32x4 accZ[2][4], accR[2][4], accH[2][4];
    #pragma unroll
    for (int ct = 0; ct < 4; ++ct) {
        int col = ct * 16 + (lane & 15);
        float bz = bxz[col] + bhz[col];
        float br = bxr[col] + bhr[col];
        float bh = bxh[col];
        #pragma unroll
        for (int rt = 0; rt < 2; ++rt) {
            accZ[rt][ct] = (f32x4){bz, bz, bz, bz};
            accR[rt][ct] = (f32x4){br, br, br, br};
            accH[rt][ct] = (f32x4){bh, bh, bh, bh};
        }
    }

    const ushort* ins[6] = { Xb, T1x, T2x, Hb, T1h, T2h };

    #pragma unroll
    for (int m = 0; m < 6; ++m) {
        #pragma unroll
        for (int kt = 0; kt < 2; ++kt) {
            bf16x8 a0 = ldA(ins[m], row0,      lane, kt, N);
            bf16x8 a1 = ldA(ins[m], row0 + 16, lane, kt, N);
            int mt = m * 2 + kt;
            #pragma unroll
            for (int ct = 0; ct < 4; ++ct) {
                bf16x8 bz8 = ldB(Bp, mt, ct, lane);
                accZ[0][ct] = MFMA(a0, bz8, accZ[0][ct]);
                accZ[1][ct] = MFMA(a1, bz8, accZ[1][ct]);
                bf16x8 br8 = ldB(Bp, 12 + mt, ct, lane);
                accR[0][ct] = MFMA(a0, br8, accR[0][ct]);
                accR[1][ct] = MFMA(a1, br8, accR[1][ct]);
                if (m < 3) {
                    bf16x8 bh8 = ldB(Bp, 24 + mt, ct, lane);
                    accH[0][ct] = MFMA(a0, bh8, accH[0][ct]);
                    accH[1][ct] = MFMA(a1, bh8, accH[1][ct]);
                }
            }
        }
    }

    #pragma unroll
    for (int rt = 0; rt < 2; ++rt) {
        #pragma unroll
        for (int ct = 0; ct < 4; ++ct) {
            int col = ct * 16 + (lane & 15);
            #pragma unroll
            for (int r = 0; r < 4; ++r) {
                int row = row0 + rt * 16 + ((lane >> 4) << 2) + r;
                if (row < N) {
                    int o = row * CH + col;
                    float z = 1.f / (1.f + expf(-accZ[rt][ct][r]));
                    float rr = 1.f / (1.f + expf(-accR[rt][ct][r]));
                    float h = H[o];
                    Zb[o] = z;
                    HRb[o] = f2bf(h * rr);
                    preH[o] = accH[rt][ct][r];
                }
            }
        }
    }
}

// ---------------- Pass B: H_new = Z*H + (1-Z)*tanh(preH + hh-conv) ----------------

__global__ __launch_bounds__(256) void k_gB(
    const ushort* __restrict__ HRb, const ushort* __restrict__ T1, const ushort* __restrict__ T2,
    const ushort* __restrict__ Bp, const float* __restrict__ bhh,
    const float* __restrict__ Zb, const float* __restrict__ H,
    float* __restrict__ out /* preH on entry */, int N)
{
    int wid = blockIdx.x * 4 + (threadIdx.x >> 6);
    int lane = threadIdx.x & 63;
    int row0 = wid * 32;
    if (row0 >= N) return;

    f32x4 acc[2][4];
    #pragma unroll
    for (int ct = 0; ct < 4; ++ct) {
        int col = ct * 16 + (lane & 15);
        float bh = bhh[col];
        #pragma unroll
        for (int rt = 0; rt < 2; ++rt) acc[rt][ct] = (f32x4){bh, bh, bh, bh};
    }

    const ushort* ins[3] = { HRb, T1, T2 };

    #pragma unroll
    for (int m = 0; m < 3; ++m) {
        #pragma unroll
        for (int kt = 0; kt < 2; ++kt) {
            bf16x8 a0 = ldA(ins[m], row0,      lane, kt, N);
            bf16x8 a1 = ldA(ins[m], row0 + 16, lane, kt, N);
            int mt = 30 + m * 2 + kt;
            #pragma unroll
            for (int ct = 0; ct < 4; ++ct) {
                bf16x8 b8 = ldB(Bp, mt, ct, lane);
                acc[0][ct] = MFMA(a0, b8, acc[0][ct]);
                acc[1][ct] = MFMA(a1, b8, acc[1][ct]);
            }
        }
    }

    #pragma unroll
    for (int rt = 0; rt < 2; ++rt) {
        #pragma unroll
        for (int ct = 0; ct < 4; ++ct) {
            int col = ct * 16 + (lane & 15);
            #pragma unroll
            for (int r = 0; r < 4; ++r) {
                int row = row0 + rt * 16 + ((lane >> 4) << 2) + r;
                if (row < N) {
                    int o = row * CH + col;
                    float pre = acc[rt][ct][r] + out[o];
                    float z = Zb[o];
                    float h = H[o];
                    out[o] = z * h + (1.f - z) * tanhf(pre);
                }
            }
        }
    }
}

// ---------------- launch ----------------

extern "C" void kernel_launch(void* const* d_in, const int* in_sizes, int n_in,
                              void* d_out, int out_size, void* d_ws, size_t ws_size,
                              hipStream_t stream) {
    const float* X   = (const float*)d_in[0];
    const int*   ei  = (const int*)d_in[1];
    const float* ew  = (const float*)d_in[2];
    const float* H   = (const float*)d_in[3];
    const float* Wxz = (const float*)d_in[4];
    const float* bxz = (const float*)d_in[5];
    const float* Whz = (const float*)d_in[6];
    const float* bhz = (const float*)d_in[7];
    const float* Wxr = (const float*)d_in[8];
    const float* bxr = (const float*)d_in[9];
    const float* Whr = (const float*)d_in[10];
    const float* bhr = (const float*)d_in[11];
    const float* Wxh = (const float*)d_in[12];
    const float* bxh = (const float*)d_in[13];
    const float* Whh = (const float*)d_in[14];
    const float* bhh = (const float*)d_in[15];

    const int N = in_sizes[0] / CH;
    const int E = in_sizes[2];
    const long long NC = (long long)N * CH;

    const int* srcI = ei;
    const int* dstI = ei + E;

    // ---- workspace layout ----
    char* p = (char*)d_ws;
    auto alloc = [&](size_t bytes) { char* r = p; p += (bytes + 255) & ~(size_t)255; return r; };
    int*    rowptr = (int*)alloc((size_t)(N + 1) * 4);
    int*    esrc   = (int*)alloc((size_t)E * 4);
    float*  elw    = (float*)alloc((size_t)E * 4);
    float*  deg    = (float*)alloc((size_t)N * 4);
    int*    cnt    = (int*)alloc((size_t)N * 4);
    ushort* Bp     = (ushort*)alloc((size_t)36 * 4 * 64 * 8 * 2);
    ushort* Xb     = (ushort*)alloc((size_t)NC * 2);
    ushort* Hb     = (ushort*)alloc((size_t)NC * 2);
    ushort* T1x    = (ushort*)alloc((size_t)NC * 2);
    ushort* T2x    = (ushort*)alloc((size_t)NC * 2);
    ushort* T1h    = (ushort*)alloc((size_t)NC * 2);
    ushort* T2h    = (ushort*)alloc((size_t)NC * 2);
    ushort* HRb    = (ushort*)alloc((size_t)NC * 2);
    float*  Zb     = (float*)alloc((size_t)NC * 4);
    float*  preH   = (float*)d_out;

    const int bE = (E + 255) / 256;
    const int bN = (N + 255) / 256;
    const int bW = (int)((N * 64 + 255) / 256);          // one wave per node
    const int nW = (N + 31) / 32;                        // gemm waves
    const int bG = (nW + 3) / 4;

    // degree + rsqrt
    hipMemsetAsync(deg, 0, (size_t)N * 4, stream);
    hipMemsetAsync(cnt, 0, (size_t)N * 4, stream);
    k_deg<<<bE, 256, 0, stream>>>(srcI, ew, deg, E);
    k_dis<<<bN, 256, 0, stream>>>(deg, N);

    // CSR build (by dst)
    k_hist<<<bE, 256, 0, stream>>>(dstI, cnt, E);
    k_scan<<<1, 1024, 0, stream>>>(cnt, rowptr, N);
    k_scatter<<<bE, 256, 0, stream>>>(srcI, dstI, ew, deg, cnt, esrc, elw, E);

    // bf16 casts + weight packing
    k_cast2<<<(int)((NC / 4 + 255) / 256), 256, 0, stream>>>(
        (const float4*)X, (const float4*)H, Xb, Hb, (int)(NC / 4));
    k_pack<<<36, 256, 0, stream>>>(Wxz, Whz, Wxr, Whr, Wxh, Whh, Bp);

    // Chebyshev bases for X and H (fused)
    k_prop_dual <<<bW, 256, 0, stream>>>(rowptr, esrc, elw, Xb, Hb, T1x, T1h, N);
    k_prop_dual2<<<bW, 256, 0, stream>>>(rowptr, esrc, elw, T1x, T1h, Xb, Hb, T2x, T2h, N);

    // Pass A: Z, H*R, preH
    k_gA<<<bG, 256, 0, stream>>>(Xb, T1x, T2x, Hb, T1h, T2h, Bp,
                                 bxz, bhz, bxr, bhr, bxh,
                                 H, Zb, HRb, preH, N);

    // Chebyshev bases for H*R (reuse T1x/T2x)
    k_prop1<<<bW, 256, 0, stream>>>(rowptr, esrc, elw, HRb, T1x, N);
    k_prop2<<<bW, 256, 0, stream>>>(rowptr, esrc, elw, T1x, HRb, T2x, N);

    // Pass B: H_new
    k_gB<<<bG, 256, 0, stream>>>(HRb, T1x, T2x, Bp, bhh, Zb, H, (float*)d_out, N);
}

// Round 4
// 397.062 us; speedup vs baseline: 3.4110x; 1.2569x over previous
//
#include <hip/hip_runtime.h>
#include <math.h>

#define CH 64   // channels (C_IN == C_OUT == 64)

typedef __attribute__((ext_vector_type(8))) short bf16x8;
typedef __attribute__((ext_vector_type(4))) float f32x4;

static __device__ __forceinline__ float bf2f(ushort u) {
    union { unsigned int i; float f; } v; v.i = ((unsigned int)u) << 16; return v.f;
}
static __device__ __forceinline__ ushort f2bf(float f) {
    union { float f; unsigned int i; } v; v.f = f;
    unsigned int lsb = (v.i >> 16) & 1;
    v.i += 0x7fffu + lsb;               // round-to-nearest-even
    return (ushort)(v.i >> 16);
}
static __device__ __forceinline__ unsigned int pack2(float a, float b) {
    return (unsigned int)f2bf(a) | ((unsigned int)f2bf(b) << 16);
}
static __device__ __forceinline__ float lo16(unsigned int u) { return bf2f((ushort)(u & 0xffffu)); }
static __device__ __forceinline__ float hi16(unsigned int u) { return bf2f((ushort)(u >> 16)); }

// ---------------- degree + dst histogram (one edge pass) ----------------

__global__ __launch_bounds__(256) void k_deghist(const int* __restrict__ src,
                                                 const int* __restrict__ dst,
                                                 const float* __restrict__ w,
                                                 float* __restrict__ deg,
                                                 int* __restrict__ cnt, int E) {
    int i = blockIdx.x * 256 + threadIdx.x;
    if (i < E) {
        atomicAdd(&deg[src[i]], w[i]);
        atomicAdd(&cnt[dst[i]], 1);
    }
}

// ---------------- 3-phase multi-block scan ----------------
// phase A: per-block (2048 elems) local exclusive scan + block total

__global__ __launch_bounds__(256) void k_scanA(const int* __restrict__ cnt,
                                               int* __restrict__ rowptr,
                                               int* __restrict__ bsum, int N) {
    __shared__ int ts[256];
    int tid = threadIdx.x;
    int base = blockIdx.x * 2048 + tid * 8;
    int v[8]; int s = 0;
    #pragma unroll
    for (int k = 0; k < 8; ++k) { int i = base + k; v[k] = (i < N) ? cnt[i] : 0; s += v[k]; }
    ts[tid] = s;
    __syncthreads();
    for (int off = 1; off < 256; off <<= 1) {
        int t = (tid >= off) ? ts[tid - off] : 0;
        __syncthreads();
        ts[tid] += t;
        __syncthreads();
    }
    int run = ts[tid] - s;     // exclusive prefix within block
    #pragma unroll
    for (int k = 0; k < 8; ++k) { int i = base + k; if (i < N) rowptr[i] = run; run += v[k]; }
    if (tid == 255) bsum[blockIdx.x] = ts[255];
}

// phase B: tiny serial scan of block sums
__global__ void k_scanB(int* __restrict__ bsum, int B) {
    if (threadIdx.x == 0) {
        int acc = 0;
        for (int b = 0; b < B; ++b) { int t = bsum[b]; bsum[b] = acc; acc += t; }
        bsum[B] = acc;
    }
}

// phase C: add block offsets, init fill cursors, fused deg->rsqrt transform
__global__ __launch_bounds__(256) void k_scanC(int* __restrict__ rowptr,
                                               int* __restrict__ cnt,
                                               const int* __restrict__ bsum,
                                               float* __restrict__ deg, int N, int B) {
    int base = blockIdx.x * 2048 + threadIdx.x * 8;
    int add = bsum[blockIdx.x];
    #pragma unroll
    for (int k = 0; k < 8; ++k) {
        int i = base + k;
        if (i < N) {
            int r = rowptr[i] + add;
            rowptr[i] = r;
            cnt[i] = r;
            float d = deg[i];
            deg[i] = (d > 0.f) ? rsqrtf(fmaxf(d, 1e-12f)) : 0.f;
        }
    }
    if (blockIdx.x == 0 && threadIdx.x == 0) rowptr[N] = bsum[B];
}

// ---------------- scatter edges into CSR order (packed metadata) ----------------

__global__ __launch_bounds__(256) void k_scatter(const int* __restrict__ src,
                                                 const int* __restrict__ dst,
                                                 const float* __restrict__ w,
                                                 const float* __restrict__ dis,
                                                 int* __restrict__ fill,
                                                 int2* __restrict__ emeta, int E) {
    int e = blockIdx.x * 256 + threadIdx.x;
    if (e < E) {
        int d = dst[e], s = src[e];
        int pos = atomicAdd(&fill[d], 1);
        float lw = -dis[s] * w[e] * dis[d];
        emeta[pos] = make_int2(s, __float_as_int(lw));
    }
}

// ---------------- cast X,H to bf16, interleaved rows [X(64) | H(64)] ----------------

__global__ __launch_bounds__(256) void k_cast2(const float4* __restrict__ X,
                                               const float4* __restrict__ H,
                                               ushort* __restrict__ XHb, int total4) {
    int i = blockIdx.x * 256 + threadIdx.x;
    if (i < total4) {
        float4 x = X[i], h = H[i];
        int node = i >> 4, c4 = i & 15;
        ushort4 xb, hb;
        xb.x = f2bf(x.x); xb.y = f2bf(x.y); xb.z = f2bf(x.z); xb.w = f2bf(x.w);
        hb.x = f2bf(h.x); hb.y = f2bf(h.y); hb.z = f2bf(h.z); hb.w = f2bf(h.w);
        *(ushort4*)(XHb + (size_t)node * 128 + c4 * 4)      = xb;
        *(ushort4*)(XHb + (size_t)node * 128 + 64 + c4 * 4) = hb;
    }
}

// ---------------- pack weights into frag-ready bf16 blobs ----------------
// Bp[mtg][ct][lane][e], mtg: z=0..11, r=12..23, h(x)=24..29, hh=30..35
// k-slot convention: k = kt*32 + (lane>>4)*8 + e  (consistent A/B -> correct)

__global__ __launch_bounds__(256) void k_pack(
    const float* __restrict__ Wxz, const float* __restrict__ Whz,
    const float* __restrict__ Wxr, const float* __restrict__ Whr,
    const float* __restrict__ Wxh, const float* __restrict__ Whh,
    ushort* __restrict__ Bp)
{
    int mtg = blockIdx.x;
    int ct = threadIdx.x >> 6;
    int lane = threadIdx.x & 63;
    const float* W; int m, kt;
    if (mtg < 12)      { int l = mtg;      m = l >> 1; kt = l & 1; W = (m < 3) ? Wxz + m * 4096 : Whz + (m - 3) * 4096; }
    else if (mtg < 24) { int l = mtg - 12; m = l >> 1; kt = l & 1; W = (m < 3) ? Wxr + m * 4096 : Whr + (m - 3) * 4096; }
    else if (mtg < 30) { int l = mtg - 24; m = l >> 1; kt = l & 1; W = Wxh + m * 4096; }
    else               { int l = mtg - 30; m = l >> 1; kt = l & 1; W = Whh + m * 4096; }
    int cout = ct * 16 + (lane & 15);
    ushort* dst = Bp + ((((mtg * 4) + ct) * 64 + lane) << 3);
    #pragma unroll
    for (int e = 0; e < 8; ++e) {
        int cin = kt * 32 + ((lane >> 4) << 3) + e;
        dst[e] = f2bf(W[cin * 64 + cout]);
    }
}

// ---------------- CSR propagation, dual (interleaved X|H rows) ----------------
// one wave per node; lane = uint = 2 bf16 channels; lanes 0-31: X, 32-63: H
// one 256B gather per edge

__global__ __launch_bounds__(256) void k_prop_dual(const int* __restrict__ rowptr,
                                                   const int2* __restrict__ emeta,
                                                   const unsigned int* __restrict__ t,
                                                   unsigned int* __restrict__ o, int N) {
    int wid = (blockIdx.x * 256 + threadIdx.x) >> 6;
    int lane = threadIdx.x & 63;
    if (wid >= N) return;
    int beg = rowptr[wid], end = rowptr[wid + 1];
    float ax = 0.f, ay = 0.f;
    int j = beg;
    for (; j + 1 < end; j += 2) {
        int2 m0 = emeta[j], m1 = emeta[j + 1];
        unsigned int p0 = t[(size_t)m0.x * 64 + lane];
        unsigned int p1 = t[(size_t)m1.x * 64 + lane];
        float l0 = __int_as_float(m0.y), l1 = __int_as_float(m1.y);
        ax = fmaf(l0, lo16(p0), ax);
        ay = fmaf(l0, hi16(p0), ay);
        ax = fmaf(l1, lo16(p1), ax);
        ay = fmaf(l1, hi16(p1), ay);
    }
    if (j < end) {
        int2 m = emeta[j];
        unsigned int p = t[(size_t)m.x * 64 + lane];
        float l = __int_as_float(m.y);
        ax = fmaf(l, lo16(p), ax);
        ay = fmaf(l, hi16(p), ay);
    }
    o[(size_t)wid * 64 + lane] = pack2(ax, ay);
}

// dual with fused Chebyshev combine: o = 2*prop(t) - t0
__global__ __launch_bounds__(256) void k_prop_dual2(const int* __restrict__ rowptr,
                                                    const int2* __restrict__ emeta,
                                                    const unsigned int* __restrict__ t,
                                                    const unsigned int* __restrict__ t0,
                                                    unsigned int* __restrict__ o, int N) {
    int wid = (blockIdx.x * 256 + threadIdx.x) >> 6;
    int lane = threadIdx.x & 63;
    if (wid >= N) return;
    int beg = rowptr[wid], end = rowptr[wid + 1];
    float ax = 0.f, ay = 0.f;
    int j = beg;
    for (; j + 1 < end; j += 2) {
        int2 m0 = emeta[j], m1 = emeta[j + 1];
        unsigned int p0 = t[(size_t)m0.x * 64 + lane];
        unsigned int p1 = t[(size_t)m1.x * 64 + lane];
        float l0 = __int_as_float(m0.y), l1 = __int_as_float(m1.y);
        ax = fmaf(l0, lo16(p0), ax);
        ay = fmaf(l0, hi16(p0), ay);
        ax = fmaf(l1, lo16(p1), ax);
        ay = fmaf(l1, hi16(p1), ay);
    }
    if (j < end) {
        int2 m = emeta[j];
        unsigned int p = t[(size_t)m.x * 64 + lane];
        float l = __int_as_float(m.y);
        ax = fmaf(l, lo16(p), ax);
        ay = fmaf(l, hi16(p), ay);
    }
    size_t oi = (size_t)wid * 64 + lane;
    unsigned int z = t0[oi];
    o[oi] = pack2(2.f * ax - lo16(z), 2.f * ay - hi16(z));
}

// ---------------- CSR propagation, single planar feature (H*R) ----------------

__global__ __launch_bounds__(256) void k_prop1(const int* __restrict__ rowptr,
                                               const int2* __restrict__ emeta,
                                               const ushort* __restrict__ t,
                                               ushort* __restrict__ out, int N) {
    int wid = (blockIdx.x * 256 + threadIdx.x) >> 6;
    int lane = threadIdx.x & 63;
    if (wid >= N) return;
    int beg = rowptr[wid], end = rowptr[wid + 1];
    float acc = 0.f;
    int j = beg;
    for (; j + 1 < end; j += 2) {
        int2 m0 = emeta[j], m1 = emeta[j + 1];
        acc = fmaf(__int_as_float(m0.y), bf2f(t[(size_t)m0.x * CH + lane]), acc);
        acc = fmaf(__int_as_float(m1.y), bf2f(t[(size_t)m1.x * CH + lane]), acc);
    }
    if (j < end) {
        int2 m = emeta[j];
        acc = fmaf(__int_as_float(m.y), bf2f(t[(size_t)m.x * CH + lane]), acc);
    }
    out[(size_t)wid * CH + lane] = f2bf(acc);
}

__global__ __launch_bounds__(256) void k_prop2(const int* __restrict__ rowptr,
                                               const int2* __restrict__ emeta,
                                               const ushort* __restrict__ t,
                                               const ushort* __restrict__ t0,
                                               ushort* __restrict__ out, int N) {
    int wid = (blockIdx.x * 256 + threadIdx.x) >> 6;
    int lane = threadIdx.x & 63;
    if (wid >= N) return;
    int beg = rowptr[wid], end = rowptr[wid + 1];
    float acc = 0.f;
    int j = beg;
    for (; j + 1 < end; j += 2) {
        int2 m0 = emeta[j], m1 = emeta[j + 1];
        acc = fmaf(__int_as_float(m0.y), bf2f(t[(size_t)m0.x * CH + lane]), acc);
        acc = fmaf(__int_as_float(m1.y), bf2f(t[(size_t)m1.x * CH + lane]), acc);
    }
    if (j < end) {
        int2 m = emeta[j];
        acc = fmaf(__int_as_float(m.y), bf2f(t[(size_t)m.x * CH + lane]), acc);
    }
    size_t o = (size_t)wid * CH + lane;
    out[o] = f2bf(2.f * acc - bf2f(t0[o]));
}

// ---------------- MFMA GEMM helpers ----------------
// wave computes 32 rows x 64 cols; k-slot: k = kt*32 + (lane>>4)*8 + e

static __device__ __forceinline__ bf16x8 ldA(const ushort* __restrict__ t, int stride,
                                             int row0, int lane, int kt, int N) {
    int row = row0 + (lane & 15);
    bf16x8 v = {};
    if (row < N) v = *(const bf16x8*)(t + (size_t)row * stride + kt * 32 + ((lane >> 4) << 3));
    return v;
}
static __device__ __forceinline__ bf16x8 ldB(const ushort* __restrict__ bp,
                                             int mt, int ct, int lane) {
    return *(const bf16x8*)(bp + ((((mt * 4) + ct) * 64 + lane) << 3));
}

#define MFMA(a, b, c) __builtin_amdgcn_mfma_f32_16x16x32_bf16(a, b, c, 0, 0, 0)

// ---------------- Pass A: Z(f32), HR(bf16), preH(f32 in d_out) ----------------

__global__ __launch_bounds__(256) void k_gA(
    const ushort* __restrict__ XHb, const ushort* __restrict__ T1xh, const ushort* __restrict__ T2xh,
    const ushort* __restrict__ Bp,
    const float* __restrict__ bxz, const float* __restrict__ bhz,
    const float* __restrict__ bxr, const float* __restrict__ bhr,
    const float* __restrict__ bxh,
    const float* __restrict__ H,
    float* __restrict__ Zb, ushort* __restrict__ HRb, float* __restrict__ preH, int N)
{
    int wid = blockIdx.x * 4 + (threadIdx.x >> 6);
    int lane = threadIdx.x & 63;
    int row0 = wid * 32;
    if (row0 >= N) return;

    f32x4 accZ[2][4], accR[2][4], accH[2][4];
    #pragma unroll
    for (int ct = 0; ct < 4; ++ct) {
        int col = ct * 16 + (lane & 15);
        float bz = bxz[col] + bhz[col];
        float br = bxr[col] + bhr[col];
        float bh = bxh[col];
        #pragma unroll
        for (int rt = 0; rt < 2; ++rt) {
            accZ[rt][ct] = (f32x4){bz, bz, bz, bz};
            accR[rt][ct] = (f32x4){br, br, br, br};
            accH[rt][ct] = (f32x4){bh, bh, bh, bh};
        }
    }

    const ushort* ins[6] = { XHb, T1xh, T2xh, XHb + 64, T1xh + 64, T2xh + 64 };

    #pragma unroll
    for (int m = 0; m < 6; ++m) {
        #pragma unroll
        for (int kt = 0; kt < 2; ++kt) {
            bf16x8 a0 = ldA(ins[m], 128, row0,      lane, kt, N);
            bf16x8 a1 = ldA(ins[m], 128, row0 + 16, lane, kt, N);
            int mt = m * 2 + kt;
            #pragma unroll
            for (int ct = 0; ct < 4; ++ct) {
                bf16x8 bz8 = ldB(Bp, mt, ct, lane);
                accZ[0][ct] = MFMA(a0, bz8, accZ[0][ct]);
                accZ[1][ct] = MFMA(a1, bz8, accZ[1][ct]);
                bf16x8 br8 = ldB(Bp, 12 + mt, ct, lane);
                accR[0][ct] = MFMA(a0, br8, accR[0][ct]);
                accR[1][ct] = MFMA(a1, br8, accR[1][ct]);
                if (m < 3) {
                    bf16x8 bh8 = ldB(Bp, 24 + mt, ct, lane);
                    accH[0][ct] = MFMA(a0, bh8, accH[0][ct]);
                    accH[1][ct] = MFMA(a1, bh8, accH[1][ct]);
                }
            }
        }
    }

    #pragma unroll
    for (int rt = 0; rt < 2; ++rt) {
        #pragma unroll
        for (int ct = 0; ct < 4; ++ct) {
            int col = ct * 16 + (lane & 15);
            #pragma unroll
            for (int r = 0; r < 4; ++r) {
                int row = row0 + rt * 16 + ((lane >> 4) << 2) + r;
                if (row < N) {
                    int o = row * CH + col;
                    float z = 1.f / (1.f + expf(-accZ[rt][ct][r]));
                    float rr = 1.f / (1.f + expf(-accR[rt][ct][r]));
                    float h = H[o];
                    Zb[o] = z;
                    HRb[o] = f2bf(h * rr);
                    preH[o] = accH[rt][ct][r];
                }
            }
        }
    }
}

// ---------------- Pass B: H_new = Z*H + (1-Z)*tanh(preH + hh-conv) ----------------

__global__ __launch_bounds__(256) void k_gB(
    const ushort* __restrict__ HRb, const ushort* __restrict__ T1, const ushort* __restrict__ T2,
    const ushort* __restrict__ Bp, const float* __restrict__ bhh,
    const float* __restrict__ Zb, const float* __restrict__ H,
    float* __restrict__ out /* preH on entry */, int N)
{
    int wid = blockIdx.x * 4 + (threadIdx.x >> 6);
    int lane = threadIdx.x & 63;
    int row0 = wid * 32;
    if (row0 >= N) return;

    f32x4 acc[2][4];
    #pragma unroll
    for (int ct = 0; ct < 4; ++ct) {
        int col = ct * 16 + (lane & 15);
        float bh = bhh[col];
        #pragma unroll
        for (int rt = 0; rt < 2; ++rt) acc[rt][ct] = (f32x4){bh, bh, bh, bh};
    }

    const ushort* ins[3] = { HRb, T1, T2 };

    #pragma unroll
    for (int m = 0; m < 3; ++m) {
        #pragma unroll
        for (int kt = 0; kt < 2; ++kt) {
            bf16x8 a0 = ldA(ins[m], 64, row0,      lane, kt, N);
            bf16x8 a1 = ldA(ins[m], 64, row0 + 16, lane, kt, N);
            int mt = 30 + m * 2 + kt;
            #pragma unroll
            for (int ct = 0; ct < 4; ++ct) {
                bf16x8 b8 = ldB(Bp, mt, ct, lane);
                acc[0][ct] = MFMA(a0, b8, acc[0][ct]);
                acc[1][ct] = MFMA(a1, b8, acc[1][ct]);
            }
        }
    }

    #pragma unroll
    for (int rt = 0; rt < 2; ++rt) {
        #pragma unroll
        for (int ct = 0; ct < 4; ++ct) {
            int col = ct * 16 + (lane & 15);
            #pragma unroll
            for (int r = 0; r < 4; ++r) {
                int row = row0 + rt * 16 + ((lane >> 4) << 2) + r;
                if (row < N) {
                    int o = row * CH + col;
                    float pre = acc[rt][ct][r] + out[o];
                    float z = Zb[o];
                    float h = H[o];
                    out[o] = z * h + (1.f - z) * tanhf(pre);
                }
            }
        }
    }
}

// ---------------- launch ----------------

extern "C" void kernel_launch(void* const* d_in, const int* in_sizes, int n_in,
                              void* d_out, int out_size, void* d_ws, size_t ws_size,
                              hipStream_t stream) {
    const float* X   = (const float*)d_in[0];
    const int*   ei  = (const int*)d_in[1];
    const float* ew  = (const float*)d_in[2];
    const float* H   = (const float*)d_in[3];
    const float* Wxz = (const float*)d_in[4];
    const float* bxz = (const float*)d_in[5];
    const float* Whz = (const float*)d_in[6];
    const float* bhz = (const float*)d_in[7];
    const float* Wxr = (const float*)d_in[8];
    const float* bxr = (const float*)d_in[9];
    const float* Whr = (const float*)d_in[10];
    const float* bhr = (const float*)d_in[11];
    const float* Wxh = (const float*)d_in[12];
    const float* bxh = (const float*)d_in[13];
    const float* Whh = (const float*)d_in[14];
    const float* bhh = (const float*)d_in[15];

    const int N = in_sizes[0] / CH;
    const int E = in_sizes[2];
    const long long NC = (long long)N * CH;

    const int* srcI = ei;
    const int* dstI = ei + E;

    // ---- workspace layout ----
    char* p = (char*)d_ws;
    auto alloc = [&](size_t bytes) { char* r = p; p += (bytes + 255) & ~(size_t)255; return r; };
    int*    rowptr = (int*)alloc((size_t)(N + 1) * 4);
    int2*   emeta  = (int2*)alloc((size_t)E * 8);
    float*  deg    = (float*)alloc((size_t)N * 8);      // deg (N) + cnt (N), contiguous
    int*    cnt    = (int*)(deg + N);
    int*    bsum   = (int*)alloc(256 * 4);
    ushort* Bp     = (ushort*)alloc((size_t)36 * 4 * 64 * 8 * 2);
    ushort* XHb    = (ushort*)alloc((size_t)NC * 2 * 2);   // interleaved X|H
    ushort* T1xh   = (ushort*)alloc((size_t)NC * 2 * 2);
    ushort* T2xh   = (ushort*)alloc((size_t)NC * 2 * 2);
    ushort* HRb    = (ushort*)alloc((size_t)NC * 2);
    ushort* T1r    = (ushort*)alloc((size_t)NC * 2);
    ushort* T2r    = (ushort*)alloc((size_t)NC * 2);
    float*  Zb     = (float*)alloc((size_t)NC * 4);
    float*  preH   = (float*)d_out;

    const int bE = (E + 255) / 256;
    const int B  = (N + 2047) / 2048;                    // scan blocks
    const int bW = (int)((N * 64 + 255) / 256);          // one wave per node
    const int nW = (N + 31) / 32;                        // gemm waves
    const int bG = (nW + 3) / 4;

    // degree + histogram (deg|cnt zeroed in one memset)
    hipMemsetAsync(deg, 0, (size_t)N * 8, stream);
    k_deghist<<<bE, 256, 0, stream>>>(srcI, dstI, ew, deg, cnt, E);

    // multi-block scan (+ fused rsqrt + cursor init)
    k_scanA<<<B, 256, 0, stream>>>(cnt, rowptr, bsum, N);
    k_scanB<<<1, 64, 0, stream>>>(bsum, B);
    k_scanC<<<B, 256, 0, stream>>>(rowptr, cnt, bsum, deg, N, B);

    // CSR scatter with packed (src, lw) metadata
    k_scatter<<<bE, 256, 0, stream>>>(srcI, dstI, ew, deg, cnt, emeta, E);

    // bf16 casts (interleaved) + weight packing
    k_cast2<<<(int)((NC / 4 + 255) / 256), 256, 0, stream>>>(
        (const float4*)X, (const float4*)H, XHb, (int)(NC / 4));
    k_pack<<<36, 256, 0, stream>>>(Wxz, Whz, Wxr, Whr, Wxh, Whh, Bp);

    // Chebyshev bases for X and H (fused, interleaved)
    k_prop_dual <<<bW, 256, 0, stream>>>(rowptr, emeta, (const unsigned int*)XHb,
                                         (unsigned int*)T1xh, N);
    k_prop_dual2<<<bW, 256, 0, stream>>>(rowptr, emeta, (const unsigned int*)T1xh,
                                         (const unsigned int*)XHb, (unsigned int*)T2xh, N);

    // Pass A: Z, H*R, preH
    k_gA<<<bG, 256, 0, stream>>>(XHb, T1xh, T2xh, Bp,
                                 bxz, bhz, bxr, bhr, bxh,
                                 H, Zb, HRb, preH, N);

    // Chebyshev bases for H*R
    k_prop1<<<bW, 256, 0, stream>>>(rowptr, emeta, HRb, T1r, N);
    k_prop2<<<bW, 256, 0, stream>>>(rowptr, emeta, T1r, HRb, T2r, N);

    // Pass B: H_new
    k_gB<<<bG, 256, 0, stream>>>(HRb, T1r, T2r, Bp, bhh, Zb, H, (float*)d_out, N);
}

// Round 5
// 297.273 us; speedup vs baseline: 4.5560x; 1.3357x over previous
//
#include <hip/hip_runtime.h>
#include <math.h>

#define CH 64   // channels (C_IN == C_OUT == 64)

typedef __attribute__((ext_vector_type(8))) short bf16x8;
typedef __attribute__((ext_vector_type(4))) float f32x4;

static __device__ __forceinline__ float bf2f(ushort u) {
    union { unsigned int i; float f; } v; v.i = ((unsigned int)u) << 16; return v.f;
}
static __device__ __forceinline__ ushort f2bf(float f) {
    union { float f; unsigned int i; } v; v.f = f;
    unsigned int lsb = (v.i >> 16) & 1;
    v.i += 0x7fffu + lsb;               // round-to-nearest-even
    return (ushort)(v.i >> 16);
}
static __device__ __forceinline__ unsigned int pack2(float a, float b) {
    return (unsigned int)f2bf(a) | ((unsigned int)f2bf(b) << 16);
}
static __device__ __forceinline__ float lo16(unsigned int u) { return bf2f((ushort)(u & 0xffffu)); }
static __device__ __forceinline__ float hi16(unsigned int u) { return bf2f((ushort)(u >> 16)); }

// ---------------- fused init: degree+hist+rank | bf16 cast | weight pack ----------------

__global__ __launch_bounds__(256) void k_init(
    const int* __restrict__ src, const int* __restrict__ dst,
    const float* __restrict__ w,
    float* __restrict__ deg, int* __restrict__ cnt, int* __restrict__ erank, int E,
    const float4* __restrict__ X, const float4* __restrict__ H,
    ushort* __restrict__ XHb, int total4,
    const float* __restrict__ Wxz, const float* __restrict__ Whz,
    const float* __restrict__ Wxr, const float* __restrict__ Whr,
    const float* __restrict__ Wxh, const float* __restrict__ Whh,
    ushort* __restrict__ Bp, int bE, int bC)
{
    int b = blockIdx.x;
    int tid = threadIdx.x;
    if (b < bE) {
        // degree over src, histogram+rank over dst
        int i = b * 256 + tid;
        if (i < E) {
            atomicAdd(&deg[src[i]], w[i]);
            erank[i] = atomicAdd(&cnt[dst[i]], 1);
        }
    } else if (b < bE + bC) {
        // cast X,H -> bf16, interleaved rows [X(64)|H(64)]
        int i = (b - bE) * 256 + tid;
        if (i < total4) {
            float4 x = X[i], h = H[i];
            int node = i >> 4, c4 = i & 15;
            ushort4 xb, hb;
            xb.x = f2bf(x.x); xb.y = f2bf(x.y); xb.z = f2bf(x.z); xb.w = f2bf(x.w);
            hb.x = f2bf(h.x); hb.y = f2bf(h.y); hb.z = f2bf(h.z); hb.w = f2bf(h.w);
            *(ushort4*)(XHb + (size_t)node * 128 + c4 * 4)      = xb;
            *(ushort4*)(XHb + (size_t)node * 128 + 64 + c4 * 4) = hb;
        }
    } else {
        // pack weights into frag-ready blobs
        // Bp[mtg][ct][lane][e], mtg: z=0..11, r=12..23, h(x)=24..29, hh=30..35
        // k-slot: k = kt*32 + (lane>>4)*8 + e (consistent A/B convention)
        int mtg = b - bE - bC;
        int ct = tid >> 6;
        int lane = tid & 63;
        const float* W; int m, kt;
        if (mtg < 12)      { int l = mtg;      m = l >> 1; kt = l & 1; W = (m < 3) ? Wxz + m * 4096 : Whz + (m - 3) * 4096; }
        else if (mtg < 24) { int l = mtg - 12; m = l >> 1; kt = l & 1; W = (m < 3) ? Wxr + m * 4096 : Whr + (m - 3) * 4096; }
        else if (mtg < 30) { int l = mtg - 24; m = l >> 1; kt = l & 1; W = Wxh + m * 4096; }
        else               { int l = mtg - 30; m = l >> 1; kt = l & 1; W = Whh + m * 4096; }
        int cout = ct * 16 + (lane & 15);
        ushort* dstp = Bp + ((((mtg * 4) + ct) * 64 + lane) << 3);
        #pragma unroll
        for (int e = 0; e < 8; ++e) {
            int cin = kt * 32 + ((lane >> 4) << 3) + e;
            dstp[e] = f2bf(W[cin * 64 + cout]);
        }
    }
}

// ---------------- 3-phase multi-block scan ----------------

__global__ __launch_bounds__(256) void k_scanA(const int* __restrict__ cnt,
                                               int* __restrict__ rowptr,
                                               int* __restrict__ bsum, int N) {
    __shared__ int ts[256];
    int tid = threadIdx.x;
    int base = blockIdx.x * 2048 + tid * 8;
    int v[8]; int s = 0;
    #pragma unroll
    for (int k = 0; k < 8; ++k) { int i = base + k; v[k] = (i < N) ? cnt[i] : 0; s += v[k]; }
    ts[tid] = s;
    __syncthreads();
    for (int off = 1; off < 256; off <<= 1) {
        int t = (tid >= off) ? ts[tid - off] : 0;
        __syncthreads();
        ts[tid] += t;
        __syncthreads();
    }
    int run = ts[tid] - s;     // exclusive prefix within block
    #pragma unroll
    for (int k = 0; k < 8; ++k) { int i = base + k; if (i < N) rowptr[i] = run; run += v[k]; }
    if (tid == 255) bsum[blockIdx.x] = ts[255];
}

__global__ void k_scanB(int* __restrict__ bsum, int B) {
    if (threadIdx.x == 0) {
        int acc = 0;
        for (int b = 0; b < B; ++b) { int t = bsum[b]; bsum[b] = acc; acc += t; }
        bsum[B] = acc;
    }
}

// phase C: add block offsets + fused deg->rsqrt transform
__global__ __launch_bounds__(256) void k_scanC(int* __restrict__ rowptr,
                                               const int* __restrict__ bsum,
                                               float* __restrict__ deg, int N, int B) {
    int base = blockIdx.x * 2048 + threadIdx.x * 8;
    int add = bsum[blockIdx.x];
    #pragma unroll
    for (int k = 0; k < 8; ++k) {
        int i = base + k;
        if (i < N) {
            rowptr[i] += add;
            float d = deg[i];
            deg[i] = (d > 0.f) ? rsqrtf(fmaxf(d, 1e-12f)) : 0.f;
        }
    }
    if (blockIdx.x == 0 && threadIdx.x == 0) rowptr[N] = bsum[B];
}

// ---------------- atomic-free scatter: pos = rowptr[dst] + rank ----------------

__global__ __launch_bounds__(256) void k_scatter(const int* __restrict__ src,
                                                 const int* __restrict__ dst,
                                                 const float* __restrict__ w,
                                                 const float* __restrict__ dis,
                                                 const int* __restrict__ rowptr,
                                                 const int* __restrict__ erank,
                                                 int2* __restrict__ emeta, int E) {
    int e = blockIdx.x * 256 + threadIdx.x;
    if (e < E) {
        int d = dst[e], s = src[e];
        int pos = rowptr[d] + erank[e];
        float lw = -dis[s] * w[e] * dis[d];
        emeta[pos] = make_int2(s, __float_as_int(lw));
    }
}

// ---------------- CSR propagation, dual (interleaved X|H rows, 256B/edge) ----------------
// one wave per node; lane = uint = 2 bf16 channels

__global__ __launch_bounds__(256) void k_prop_dual(const int* __restrict__ rowptr,
                                                   const int2* __restrict__ emeta,
                                                   const unsigned int* __restrict__ t,
                                                   unsigned int* __restrict__ o, int N) {
    int wid = (blockIdx.x * 256 + threadIdx.x) >> 6;
    int lane = threadIdx.x & 63;
    if (wid >= N) return;
    int beg = rowptr[wid], end = rowptr[wid + 1];
    float ax = 0.f, ay = 0.f;
    int j = beg;
    for (; j + 3 < end; j += 4) {
        int2 m0 = emeta[j], m1 = emeta[j + 1], m2 = emeta[j + 2], m3 = emeta[j + 3];
        unsigned int p0 = t[(size_t)m0.x * 64 + lane];
        unsigned int p1 = t[(size_t)m1.x * 64 + lane];
        unsigned int p2 = t[(size_t)m2.x * 64 + lane];
        unsigned int p3 = t[(size_t)m3.x * 64 + lane];
        float l0 = __int_as_float(m0.y), l1 = __int_as_float(m1.y);
        float l2 = __int_as_float(m2.y), l3 = __int_as_float(m3.y);
        ax = fmaf(l0, lo16(p0), ax); ay = fmaf(l0, hi16(p0), ay);
        ax = fmaf(l1, lo16(p1), ax); ay = fmaf(l1, hi16(p1), ay);
        ax = fmaf(l2, lo16(p2), ax); ay = fmaf(l2, hi16(p2), ay);
        ax = fmaf(l3, lo16(p3), ax); ay = fmaf(l3, hi16(p3), ay);
    }
    for (; j < end; ++j) {
        int2 m = emeta[j];
        unsigned int p = t[(size_t)m.x * 64 + lane];
        float l = __int_as_float(m.y);
        ax = fmaf(l, lo16(p), ax); ay = fmaf(l, hi16(p), ay);
    }
    o[(size_t)wid * 64 + lane] = pack2(ax, ay);
}

__global__ __launch_bounds__(256) void k_prop_dual2(const int* __restrict__ rowptr,
                                                    const int2* __restrict__ emeta,
                                                    const unsigned int* __restrict__ t,
                                                    const unsigned int* __restrict__ t0,
                                                    unsigned int* __restrict__ o, int N) {
    int wid = (blockIdx.x * 256 + threadIdx.x) >> 6;
    int lane = threadIdx.x & 63;
    if (wid >= N) return;
    int beg = rowptr[wid], end = rowptr[wid + 1];
    float ax = 0.f, ay = 0.f;
    int j = beg;
    for (; j + 3 < end; j += 4) {
        int2 m0 = emeta[j], m1 = emeta[j + 1], m2 = emeta[j + 2], m3 = emeta[j + 3];
        unsigned int p0 = t[(size_t)m0.x * 64 + lane];
        unsigned int p1 = t[(size_t)m1.x * 64 + lane];
        unsigned int p2 = t[(size_t)m2.x * 64 + lane];
        unsigned int p3 = t[(size_t)m3.x * 64 + lane];
        float l0 = __int_as_float(m0.y), l1 = __int_as_float(m1.y);
        float l2 = __int_as_float(m2.y), l3 = __int_as_float(m3.y);
        ax = fmaf(l0, lo16(p0), ax); ay = fmaf(l0, hi16(p0), ay);
        ax = fmaf(l1, lo16(p1), ax); ay = fmaf(l1, hi16(p1), ay);
        ax = fmaf(l2, lo16(p2), ax); ay = fmaf(l2, hi16(p2), ay);
        ax = fmaf(l3, lo16(p3), ax); ay = fmaf(l3, hi16(p3), ay);
    }
    for (; j < end; ++j) {
        int2 m = emeta[j];
        unsigned int p = t[(size_t)m.x * 64 + lane];
        float l = __int_as_float(m.y);
        ax = fmaf(l, lo16(p), ax); ay = fmaf(l, hi16(p), ay);
    }
    size_t oi = (size_t)wid * 64 + lane;
    unsigned int z = t0[oi];
    o[oi] = pack2(2.f * ax - lo16(z), 2.f * ay - hi16(z));
}

// ---------------- CSR propagation, single feature (H*R): 2 nodes/wave ----------------
// 32-lane subgroup per node; lane = uint = 2 bf16 channels (128B/edge)

__global__ __launch_bounds__(256) void k_prop1(const int* __restrict__ rowptr,
                                               const int2* __restrict__ emeta,
                                               const unsigned int* __restrict__ t,
                                               unsigned int* __restrict__ out, int N) {
    int wv = (blockIdx.x * 256 + threadIdx.x) >> 6;
    int lane = threadIdx.x & 63;
    int node = wv * 2 + (lane >> 5);
    int sl = lane & 31;
    if (node >= N) return;
    int beg = rowptr[node], end = rowptr[node + 1];
    float ax = 0.f, ay = 0.f;
    int j = beg;
    for (; j + 3 < end; j += 4) {
        int2 m0 = emeta[j], m1 = emeta[j + 1], m2 = emeta[j + 2], m3 = emeta[j + 3];
        unsigned int p0 = t[(size_t)m0.x * 32 + sl];
        unsigned int p1 = t[(size_t)m1.x * 32 + sl];
        unsigned int p2 = t[(size_t)m2.x * 32 + sl];
        unsigned int p3 = t[(size_t)m3.x * 32 + sl];
        float l0 = __int_as_float(m0.y), l1 = __int_as_float(m1.y);
        float l2 = __int_as_float(m2.y), l3 = __int_as_float(m3.y);
        ax = fmaf(l0, lo16(p0), ax); ay = fmaf(l0, hi16(p0), ay);
        ax = fmaf(l1, lo16(p1), ax); ay = fmaf(l1, hi16(p1), ay);
        ax = fmaf(l2, lo16(p2), ax); ay = fmaf(l2, hi16(p2), ay);
        ax = fmaf(l3, lo16(p3), ax); ay = fmaf(l3, hi16(p3), ay);
    }
    for (; j < end; ++j) {
        int2 m = emeta[j];
        unsigned int p = t[(size_t)m.x * 32 + sl];
        float l = __int_as_float(m.y);
        ax = fmaf(l, lo16(p), ax); ay = fmaf(l, hi16(p), ay);
    }
    out[(size_t)node * 32 + sl] = pack2(ax, ay);
}

__global__ __launch_bounds__(256) void k_prop2(const int* __restrict__ rowptr,
                                               const int2* __restrict__ emeta,
                                               const unsigned int* __restrict__ t,
                                               const unsigned int* __restrict__ t0,
                                               unsigned int* __restrict__ out, int N) {
    int wv = (blockIdx.x * 256 + threadIdx.x) >> 6;
    int lane = threadIdx.x & 63;
    int node = wv * 2 + (lane >> 5);
    int sl = lane & 31;
    if (node >= N) return;
    int beg = rowptr[node], end = rowptr[node + 1];
    float ax = 0.f, ay = 0.f;
    int j = beg;
    for (; j + 3 < end; j += 4) {
        int2 m0 = emeta[j], m1 = emeta[j + 1], m2 = emeta[j + 2], m3 = emeta[j + 3];
        unsigned int p0 = t[(size_t)m0.x * 32 + sl];
        unsigned int p1 = t[(size_t)m1.x * 32 + sl];
        unsigned int p2 = t[(size_t)m2.x * 32 + sl];
        unsigned int p3 = t[(size_t)m3.x * 32 + sl];
        float l0 = __int_as_float(m0.y), l1 = __int_as_float(m1.y);
        float l2 = __int_as_float(m2.y), l3 = __int_as_float(m3.y);
        ax = fmaf(l0, lo16(p0), ax); ay = fmaf(l0, hi16(p0), ay);
        ax = fmaf(l1, lo16(p1), ax); ay = fmaf(l1, hi16(p1), ay);
        ax = fmaf(l2, lo16(p2), ax); ay = fmaf(l2, hi16(p2), ay);
        ax = fmaf(l3, lo16(p3), ax); ay = fmaf(l3, hi16(p3), ay);
    }
    for (; j < end; ++j) {
        int2 m = emeta[j];
        unsigned int p = t[(size_t)m.x * 32 + sl];
        float l = __int_as_float(m.y);
        ax = fmaf(l, lo16(p), ax); ay = fmaf(l, hi16(p), ay);
    }
    size_t oi = (size_t)node * 32 + sl;
    unsigned int z = t0[oi];
    out[oi] = pack2(2.f * ax - lo16(z), 2.f * ay - hi16(z));
}

// ---------------- MFMA GEMM helpers ----------------
// wave computes 32 rows x 64 cols; k-slot: k = kt*32 + (lane>>4)*8 + e

static __device__ __forceinline__ bf16x8 ldA(const ushort* __restrict__ t, int stride,
                                             int row0, int lane, int kt, int N) {
    int row = row0 + (lane & 15);
    bf16x8 v = {};
    if (row < N) v = *(const bf16x8*)(t + (size_t)row * stride + kt * 32 + ((lane >> 4) << 3));
    return v;
}
static __device__ __forceinline__ bf16x8 ldB(const ushort* __restrict__ bp,
                                             int mt, int ct, int lane) {
    return *(const bf16x8*)(bp + ((((mt * 4) + ct) * 64 + lane) << 3));
}

#define MFMA(a, b, c) __builtin_amdgcn_mfma_f32_16x16x32_bf16(a, b, c, 0, 0, 0)

// ---------------- Pass A: Z(bf16), HR(bf16), preH(f32 in d_out) ----------------

__global__ __launch_bounds__(256) void k_gA(
    const ushort* __restrict__ XHb, const ushort* __restrict__ T1xh, const ushort* __restrict__ T2xh,
    const ushort* __restrict__ Bp,
    const float* __restrict__ bxz, const float* __restrict__ bhz,
    const float* __restrict__ bxr, const float* __restrict__ bhr,
    const float* __restrict__ bxh,
    const float* __restrict__ H,
    ushort* __restrict__ Zb, ushort* __restrict__ HRb, float* __restrict__ preH, int N)
{
    int wid = blockIdx.x * 4 + (threadIdx.x >> 6);
    int lane = threadIdx.x & 63;
    int row0 = wid * 32;
    if (row0 >= N) return;

    f32x4 accZ[2][4], accR[2][4], accH[2][4];
    #pragma unroll
    for (int ct = 0; ct < 4; ++ct) {
        int col = ct * 16 + (lane & 15);
        float bz = bxz[col] + bhz[col];
        float br = bxr[col] + bhr[col];
        float bh = bxh[col];
        #pragma unroll
        for (int rt = 0; rt < 2; ++rt) {
            accZ[rt][ct] = (f32x4){bz, bz, bz, bz};
            accR[rt][ct] = (f32x4){br, br, br, br};
            accH[rt][ct] = (f32x4){bh, bh, bh, bh};
        }
    }

    const ushort* ins[6] = { XHb, T1xh, T2xh, XHb + 64, T1xh + 64, T2xh + 64 };

    #pragma unroll
    for (int m = 0; m < 6; ++m) {
        #pragma unroll
        for (int kt = 0; kt < 2; ++kt) {
            bf16x8 a0 = ldA(ins[m], 128, row0,      lane, kt, N);
            bf16x8 a1 = ldA(ins[m], 128, row0 + 16, lane, kt, N);
            int mt = m * 2 + kt;
            #pragma unroll
            for (int ct = 0; ct < 4; ++ct) {
                bf16x8 bz8 = ldB(Bp, mt, ct, lane);
                accZ[0][ct] = MFMA(a0, bz8, accZ[0][ct]);
                accZ[1][ct] = MFMA(a1, bz8, accZ[1][ct]);
                bf16x8 br8 = ldB(Bp, 12 + mt, ct, lane);
                accR[0][ct] = MFMA(a0, br8, accR[0][ct]);
                accR[1][ct] = MFMA(a1, br8, accR[1][ct]);
                if (m < 3) {
                    bf16x8 bh8 = ldB(Bp, 24 + mt, ct, lane);
                    accH[0][ct] = MFMA(a0, bh8, accH[0][ct]);
                    accH[1][ct] = MFMA(a1, bh8, accH[1][ct]);
                }
            }
        }
    }

    #pragma unroll
    for (int rt = 0; rt < 2; ++rt) {
        #pragma unroll
        for (int ct = 0; ct < 4; ++ct) {
            int col = ct * 16 + (lane & 15);
            #pragma unroll
            for (int r = 0; r < 4; ++r) {
                int row = row0 + rt * 16 + ((lane >> 4) << 2) + r;
                if (row < N) {
                    int o = row * CH + col;
                    float z = 1.f / (1.f + expf(-accZ[rt][ct][r]));
                    float rr = 1.f / (1.f + expf(-accR[rt][ct][r]));
                    float h = H[o];
                    Zb[o] = f2bf(z);
                    HRb[o] = f2bf(h * rr);
                    preH[o] = accH[rt][ct][r];
                }
            }
        }
    }
}

// ---------------- Pass B: H_new = Z*H + (1-Z)*tanh(preH + hh-conv) ----------------

__global__ __launch_bounds__(256) void k_gB(
    const ushort* __restrict__ HRb, const ushort* __restrict__ T1, const ushort* __restrict__ T2,
    const ushort* __restrict__ Bp, const float* __restrict__ bhh,
    const ushort* __restrict__ Zb, const float* __restrict__ H,
    float* __restrict__ out /* preH on entry */, int N)
{
    int wid = blockIdx.x * 4 + (threadIdx.x >> 6);
    int lane = threadIdx.x & 63;
    int row0 = wid * 32;
    if (row0 >= N) return;

    f32x4 acc[2][4];
    #pragma unroll
    for (int ct = 0; ct < 4; ++ct) {
        int col = ct * 16 + (lane & 15);
        float bh = bhh[col];
        #pragma unroll
        for (int rt = 0; rt < 2; ++rt) acc[rt][ct] = (f32x4){bh, bh, bh, bh};
    }

    const ushort* ins[3] = { HRb, T1, T2 };

    #pragma unroll
    for (int m = 0; m < 3; ++m) {
        #pragma unroll
        for (int kt = 0; kt < 2; ++kt) {
            bf16x8 a0 = ldA(ins[m], 64, row0,      lane, kt, N);
            bf16x8 a1 = ldA(ins[m], 64, row0 + 16, lane, kt, N);
            int mt = 30 + m * 2 + kt;
            #pragma unroll
            for (int ct = 0; ct < 4; ++ct) {
                bf16x8 b8 = ldB(Bp, mt, ct, lane);
                acc[0][ct] = MFMA(a0, b8, acc[0][ct]);
                acc[1][ct] = MFMA(a1, b8, acc[1][ct]);
            }
        }
    }

    #pragma unroll
    for (int rt = 0; rt < 2; ++rt) {
        #pragma unroll
        for (int ct = 0; ct < 4; ++ct) {
            int col = ct * 16 + (lane & 15);
            #pragma unroll
            for (int r = 0; r < 4; ++r) {
                int row = row0 + rt * 16 + ((lane >> 4) << 2) + r;
                if (row < N) {
                    int o = row * CH + col;
                    float pre = acc[rt][ct][r] + out[o];
                    float z = bf2f(Zb[o]);
                    float h = H[o];
                    out[o] = z * h + (1.f - z) * tanhf(pre);
                }
            }
        }
    }
}

// ---------------- launch ----------------

extern "C" void kernel_launch(void* const* d_in, const int* in_sizes, int n_in,
                              void* d_out, int out_size, void* d_ws, size_t ws_size,
                              hipStream_t stream) {
    const float* X   = (const float*)d_in[0];
    const int*   ei  = (const int*)d_in[1];
    const float* ew  = (const float*)d_in[2];
    const float* H   = (const float*)d_in[3];
    const float* Wxz = (const float*)d_in[4];
    const float* bxz = (const float*)d_in[5];
    const float* Whz = (const float*)d_in[6];
    const float* bhz = (const float*)d_in[7];
    const float* Wxr = (const float*)d_in[8];
    const float* bxr = (const float*)d_in[9];
    const float* Whr = (const float*)d_in[10];
    const float* bhr = (const float*)d_in[11];
    const float* Wxh = (const float*)d_in[12];
    const float* bxh = (const float*)d_in[13];
    const float* Whh = (const float*)d_in[14];
    const float* bhh = (const float*)d_in[15];

    const int N = in_sizes[0] / CH;
    const int E = in_sizes[2];
    const long long NC = (long long)N * CH;

    const int* srcI = ei;
    const int* dstI = ei + E;

    // ---- workspace layout ----
    char* p = (char*)d_ws;
    auto alloc = [&](size_t bytes) { char* r = p; p += (bytes + 255) & ~(size_t)255; return r; };
    int*    rowptr = (int*)alloc((size_t)(N + 1) * 4);
    int2*   emeta  = (int2*)alloc((size_t)E * 8);
    int*    erank  = (int*)alloc((size_t)E * 4);
    float*  deg    = (float*)alloc((size_t)N * 8);      // deg (N) + cnt (N), contiguous
    int*    cnt    = (int*)(deg + N);
    int*    bsum   = (int*)alloc(256 * 4);
    ushort* Bp     = (ushort*)alloc((size_t)36 * 4 * 64 * 8 * 2);
    ushort* XHb    = (ushort*)alloc((size_t)NC * 2 * 2);   // interleaved X|H
    ushort* T1xh   = (ushort*)alloc((size_t)NC * 2 * 2);
    ushort* T2xh   = (ushort*)alloc((size_t)NC * 2 * 2);
    ushort* HRb    = (ushort*)alloc((size_t)NC * 2);
    ushort* T1r    = (ushort*)alloc((size_t)NC * 2);
    ushort* T2r    = (ushort*)alloc((size_t)NC * 2);
    ushort* Zb     = (ushort*)alloc((size_t)NC * 2);
    float*  preH   = (float*)d_out;

    const int total4 = (int)(NC / 4);
    const int bE = (E + 255) / 256;
    const int bC = (total4 + 255) / 256;
    const int B  = (N + 2047) / 2048;                    // scan blocks
    const int bW = (int)((N * 64 + 255) / 256);          // one wave per node
    const int bW2 = (int)((((N + 1) / 2) * 64 + 255) / 256); // 2 nodes per wave
    const int nW = (N + 31) / 32;                        // gemm waves
    const int bG = (nW + 3) / 4;

    // fused init: degree+hist+rank | cast | pack
    hipMemsetAsync(deg, 0, (size_t)N * 8, stream);
    k_init<<<bE + bC + 36, 256, 0, stream>>>(srcI, dstI, ew, deg, cnt, erank, E,
                                             (const float4*)X, (const float4*)H, XHb, total4,
                                             Wxz, Whz, Wxr, Whr, Wxh, Whh, Bp, bE, bC);

    // multi-block scan (+ fused rsqrt)
    k_scanA<<<B, 256, 0, stream>>>(cnt, rowptr, bsum, N);
    k_scanB<<<1, 64, 0, stream>>>(bsum, B);
    k_scanC<<<B, 256, 0, stream>>>(rowptr, bsum, deg, N, B);

    // atomic-free CSR scatter
    k_scatter<<<bE, 256, 0, stream>>>(srcI, dstI, ew, deg, rowptr, erank, emeta, E);

    // Chebyshev bases for X and H (fused, interleaved)
    k_prop_dual <<<bW, 256, 0, stream>>>(rowptr, emeta, (const unsigned int*)XHb,
                                         (unsigned int*)T1xh, N);
    k_prop_dual2<<<bW, 256, 0, stream>>>(rowptr, emeta, (const unsigned int*)T1xh,
                                         (const unsigned int*)XHb, (unsigned int*)T2xh, N);

    // Pass A: Z, H*R, preH
    k_gA<<<bG, 256, 0, stream>>>(XHb, T1xh, T2xh, Bp,
                                 bxz, bhz, bxr, bhr, bxh,
                                 H, Zb, HRb, preH, N);

    // Chebyshev bases for H*R (2 nodes/wave)
    k_prop1<<<bW2, 256, 0, stream>>>(rowptr, emeta, (const unsigned int*)HRb,
                                     (unsigned int*)T1r, N);
    k_prop2<<<bW2, 256, 0, stream>>>(rowptr, emeta, (const unsigned int*)T1r,
                                     (const unsigned int*)HRb, (unsigned int*)T2r, N);

    // Pass B: H_new
    k_gB<<<bG, 256, 0, stream>>>(HRb, T1r, T2r, Bp, bhh, Zb, H, (float*)d_out, N);
}